// Round 1
// 342.995 us; speedup vs baseline: 1.0439x; 1.0439x over previous
//
#include <hip/hip_runtime.h>

#define BATCH 4
#define SEQ 2048
#define HEADS 16
#define DHEAD 64
#define HID 1024
#define MROWS (BATCH * SEQ)   // 8192
#define QSCALE 0.1803368801111092f   // 0.125 * log2(e): exp2 domain

typedef unsigned short u16;
typedef unsigned int u32;
typedef __attribute__((ext_vector_type(4))) float f32x4;
typedef __attribute__((ext_vector_type(8))) short bf16x8;
typedef __attribute__((ext_vector_type(2))) unsigned int u32x2;

#define MFMA16(a, b, c) __builtin_amdgcn_mfma_f32_16x16x32_bf16((a), (b), (c), 0, 0, 0)
#define EXP2F(x) __builtin_amdgcn_exp2f(x)

// f32 -> bf16 round-to-nearest-even (finite inputs)
__device__ __forceinline__ u16 f2bf(float f) {
  union { float f; u32 i; } x; x.f = f;
  u32 r = x.i + 0x7fffu + ((x.i >> 16) & 1u);
  return (u16)(r >> 16);
}

// packed f32 pair -> bf16 pair (RNE), one VALU op.  No builtin on gfx950 ->
// inline asm (T12 primitive).  D[15:0]=bf16(a), D[31:16]=bf16(b).
__device__ __forceinline__ u32 cvtpk(float a, float b) {
  u32 d;
  asm("v_cvt_pk_bf16_f32 %0, %1, %2" : "=v"(d) : "v"(a), "v"(b));
  return d;
}

// async global->LDS, 16 B/lane.  LDS dest must be wave-uniform base + lane*16.
__device__ __forceinline__ void lds16(const u16* g, u16* s) {
  __builtin_amdgcn_global_load_lds(
      (const __attribute__((address_space(1))) void*)g,
      (__attribute__((address_space(3))) void*)s, 16, 0, 0);
}

// VALU staging: 8 fp32 -> 8 bf16 (fallback paths + cvt kernel)
__device__ __forceinline__ void stage8f(const float* __restrict__ g, u16* s) {
  const float4 a = *(const float4*)g;
  const float4 b = *(const float4*)(g + 4);
  ushort4 lo, hi;
  lo.x = f2bf(a.x); lo.y = f2bf(a.y); lo.z = f2bf(a.z); lo.w = f2bf(a.w);
  hi.x = f2bf(b.x); hi.y = f2bf(b.y); hi.z = f2bf(b.z); hi.w = f2bf(b.w);
  *(ushort4*)s = lo;
  *(ushort4*)(s + 4) = hi;
}

// fp32 -> bf16 for up to 7 tensors in one launch.
// y(+yoff)=0..2: activations (n = SEG).  y=3: the 4 weights, packed as one
// 4*WSEG range (WSEG = 1<<20; j = i>>20 selects the tensor).
struct CvtArgs {
  const float* src[7];
  u16* dst[7];
};
__global__ __launch_bounds__(256) void cvt7(CvtArgs args, int yoff, int nact) {
  const int y = blockIdx.y + yoff;
  const int i = (blockIdx.x * 256 + threadIdx.x) * 8;
  if (y < 3) {
    if (i < nact) stage8f(args.src[y] + i, args.dst[y] + i);
  } else {
    if (i < 4 * (1 << 20)) {
      const int j = i >> 20, off = i & ((1 << 20) - 1);
      stage8f(args.src[3 + j] + off, args.dst[3 + j] + off);
    }
  }
}

// 128x128x(BK=32) MFMA GEMM core: C = A[M,K] @ W[N,K]^T, fp32 accum.
// ADMA/BDMA=1: operand bf16, global_load_lds; =0: fp32, VALU convert-stage.
// LDS chunk-slot XOR swizzle (slot = chunk ^ ((row>>1)&3)) -> conflict-free
// ds_read_b128 fragments while keeping the global_load_lds lane->slot contract.
template<bool ADMA, bool BDMA>
__device__ __forceinline__ void gemm_core(
    const void* __restrict__ Av, const void* __restrict__ Wv,
    int tid, int m0, int n0, u16* As, u16* Bs, f32x4 (&acc)[4][4])
{
  const int srow = tid >> 2, cslot = tid & 3;
  const int gc = cslot ^ ((srow >> 1) & 3);   // swizzled global chunk
  const int w = tid >> 6, l = tid & 63;
  const int quad = l >> 4, l15 = l & 15;
  const int sw = (l15 >> 1) & 3;
  const int wm = (w & 1) << 6, wn = (w >> 1) << 6;

  for (int k0 = 0; k0 < HID; k0 += 32) {
    if (ADMA) {
      const u16* ag = (const u16*)Av + (size_t)(m0 + srow) * HID + k0 + gc * 8;
      lds16(ag, &As[tid * 8]);
      lds16(ag + (size_t)64 * HID, &As[2048 + tid * 8]);
    } else {
      const float* ag = (const float*)Av + (size_t)(m0 + srow) * HID + k0 + gc * 8;
      stage8f(ag, &As[srow * 32 + cslot * 8]);
      stage8f(ag + (size_t)64 * HID, &As[(64 + srow) * 32 + cslot * 8]);
    }
    if (BDMA) {
      const u16* bg = (const u16*)Wv + (size_t)(n0 + srow) * HID + k0 + gc * 8;
      lds16(bg, &Bs[tid * 8]);
      lds16(bg + (size_t)64 * HID, &Bs[2048 + tid * 8]);
    } else {
      const float* bg = (const float*)Wv + (size_t)(n0 + srow) * HID + k0 + gc * 8;
      stage8f(bg, &Bs[srow * 32 + cslot * 8]);
      stage8f(bg + (size_t)64 * HID, &Bs[(64 + srow) * 32 + cslot * 8]);
    }
    __syncthreads();

    bf16x8 a[4], b[4];
    #pragma unroll
    for (int i = 0; i < 4; ++i)
      a[i] = *(const bf16x8*)&As[(wm + i * 16 + l15) * 32 + (quad ^ sw) * 8];
    #pragma unroll
    for (int j = 0; j < 4; ++j)
      b[j] = *(const bf16x8*)&Bs[(wn + j * 16 + l15) * 32 + (quad ^ sw) * 8];
    #pragma unroll
    for (int i = 0; i < 4; ++i)
      #pragma unroll
      for (int j = 0; j < 4; ++j)
        acc[i][j] = MFMA16(a[i], b[j], acc[i][j]);
    __syncthreads();
  }
}

// Fused QKV projection.  blockIdx.z selects q/k/v.  Epilogues:
//  z=0 (Q): *QSCALE and *mask(query row) -> masked rows produce logits 0.
//  z=1 (K): plain bf16 [bh][s][64].
//  z=2 (V): bf16 [bh][d][s], keys PERMUTED within each 64-group
//           (key s0 -> slot (s0&15)*4 + (s0>>4)) to match attention P-layout.
template<bool ADMA, bool BDMA>
__global__ __launch_bounds__(256) void gemm_qkv(
    const void* __restrict__ xq, const void* __restrict__ xk,
    const void* __restrict__ xv,
    const void* __restrict__ wqv, const void* __restrict__ wkv,
    const void* __restrict__ wvv,
    const float* __restrict__ bq, const float* __restrict__ bk,
    const float* __restrict__ bv, const int* __restrict__ Mask,
    u16* __restrict__ qh, u16* __restrict__ kh, u16* __restrict__ vt)
{
  __shared__ u16 As[128 * 32];
  __shared__ u16 Bs[128 * 32];
  const int z = blockIdx.z;
  const void* A = (z == 0) ? xq : (z == 1) ? xk : xv;
  const void* W = (z == 0) ? wqv : (z == 1) ? wkv : wvv;
  const float* Bias = (z == 0) ? bq : (z == 1) ? bk : bv;

  const int tid = threadIdx.x;
  const int m0 = blockIdx.x << 7, n0 = blockIdx.y << 7;
  f32x4 acc[4][4] = {};
  gemm_core<ADMA, BDMA>(A, W, tid, m0, n0, As, Bs, acc);

  const int w = tid >> 6, l = tid & 63;
  const int quad = l >> 4, l15 = l & 15;
  const int wm = (w & 1) << 6, wn = (w >> 1) << 6;

  if (z <= 1) {
    u16* Out = (z == 0) ? qh : kh;
    #pragma unroll
    for (int i = 0; i < 4; ++i) {
      float fl[4];
      #pragma unroll
      for (int r = 0; r < 4; ++r) {
        const int m = m0 + wm + i * 16 + (quad << 2) + r;
        fl[r] = (z == 0) ? (Mask[m] ? QSCALE : 0.f) : 1.f;
      }
      #pragma unroll
      for (int j = 0; j < 4; ++j) {
        const int n = n0 + wn + j * 16 + l15;
        const float bias = Bias[n];
        const int h = n >> 6, d = n & 63;
        #pragma unroll
        for (int r = 0; r < 4; ++r) {
          const int m = m0 + wm + i * 16 + (quad << 2) + r;
          const int bb = m >> 11, s = m & (SEQ - 1);
          Out[((size_t)(bb * HEADS + h) * SEQ + s) * DHEAD + d] =
              f2bf((acc[i][j][r] + bias) * fl[r]);
        }
      }
    }
  } else {
    const int sblk = (m0 + wm) & (SEQ - 1);
    const int bb = (m0 + wm) >> 11;
    #pragma unroll
    for (int j = 0; j < 4; ++j) {
      const int n = n0 + wn + j * 16 + l15;
      const float bias = Bias[n];
      const int h = n >> 6, d = n & 63;
      u16* base = vt + ((size_t)(bb * HEADS + h) * DHEAD + d) * SEQ + sblk;
      #pragma unroll
      for (int r = 0; r < 4; ++r) {
        u32x2 pk;
        pk.x = cvtpk(acc[0][j][r] + bias, acc[1][j][r] + bias);
        pk.y = cvtpk(acc[2][j][r] + bias, acc[3][j][r] + bias);
        *(u32x2*)(base + ((quad << 2) + r) * 4) = pk;
      }
    }
  }
}

// Output projection: fp32 out = hidden(bf16) @ wo^T + bo
template<bool BDMA>
__global__ __launch_bounds__(256) void gemm_out(
    const u16* __restrict__ hidden, const void* __restrict__ wov,
    const float* __restrict__ bo, float* __restrict__ Out)
{
  __shared__ u16 As[128 * 32];
  __shared__ u16 Bs[128 * 32];
  const int tid = threadIdx.x;
  const int m0 = blockIdx.x << 7, n0 = blockIdx.y << 7;
  f32x4 acc[4][4] = {};
  gemm_core<true, BDMA>(hidden, wov, tid, m0, n0, As, Bs, acc);

  const int w = tid >> 6, l = tid & 63;
  const int quad = l >> 4, l15 = l & 15;
  const int wm = (w & 1) << 6, wn = (w >> 1) << 6;
  #pragma unroll
  for (int j = 0; j < 4; ++j) {
    const int n = n0 + wn + j * 16 + l15;
    const float bias = bo[n];
    #pragma unroll
    for (int i = 0; i < 4; ++i) {
      const int mb = m0 + wm + i * 16 + (quad << 2);
      #pragma unroll
      for (int r = 0; r < 4; ++r)
        Out[(size_t)(mb + r) * HID + n] = acc[i][j][r] + bias;
    }
  }
}

// Flash attention, no-max softmax.  128-thread blocks (2 waves); each wave
// owns 64 queries x all 64 keys of the tile.
//
// Pipelined tile loop (T3/T4 counted-vmcnt, raw s_barrier -- __syncthreads
// would drain vmcnt(0) and kill the prefetch):
//   top:      s_waitcnt vmcnt(4)  -> K(t) landed        ; barrier
//   QK^T      (reads Ks)                                ; barrier
//   issue     K(t+1) -> Ks (4 loads), V(t+1) -> Vt[cur^1] (4 loads)
//   exp/P     (wave-private Ps rows, v_cvt_pk_bf16_f32 pack)
//   pre-PV:   s_waitcnt vmcnt(8)  -> V(t) landed        ; barrier
//   PV        (reads Vt[cur], Ps)
// K is restaged in place (reads finished at the post-QK barrier); V is
// double-buffered so its prefetch spans a full iteration.  Issue order is
// all-K-then-all-V so the counted waits isolate the right group.
// LDS 40 KB (QP 16K + Ks 8K + Vt 2x8K) = exactly 4 blocks/CU (160 KB).
// Last iteration stages tile 0 again (wrapped) to keep counts uniform; a
// final vmcnt(0) drains the LDS-DMA before endpgm.
// XCD remap: bh = lin&63 -> all 16 q-tiles of a head on one XCD's L2.
__global__ __launch_bounds__(128, 2) void attn_mfma(
    const u16* __restrict__ QH, const u16* __restrict__ KH,
    const u16* __restrict__ VT, u16* __restrict__ Hidden)
{
  __shared__ u16 QP[128 * 64];     // 16 KB: Qs [2][128x32] then Ps [128][64]
  __shared__ u16 Ks[2][2048];      // 8 KB, single-buffered (restage post-QK)
  __shared__ u16 Vt[2][2][2048];   // 16 KB, double-buffered [buf][hh]

  const int tid = threadIdx.x;     // 0..127
  const int w = tid >> 6, l = tid & 63;
  const int quad = l >> 4, l15 = l & 15;
  const int sw = (l15 >> 1) & 3;
  const int srow = tid >> 2, cslot = tid & 3;
  const int gc = cslot ^ ((srow >> 1) & 3);   // staging swizzle (global side)

  const int lin = blockIdx.y * 16 + blockIdx.x;
  const int bh = lin & 63, b = bh >> 4, h = bh & 15;
  const int q0 = (lin >> 6) << 7;

  const u16* qbase = QH + (size_t)bh * SEQ * DHEAD;
  const u16* kbase = KH + (size_t)bh * SEQ * DHEAD;
  const u16* vbase = VT + (size_t)bh * DHEAD * SEQ;

  // prologue: Q (8 loads), then K(0) (4), then V(0) (4) -- order matters for
  // the counted waits below.
  #pragma unroll
  for (int hh = 0; hh < 2; ++hh)
    #pragma unroll
    for (int part = 0; part < 4; ++part)
      lds16(qbase + (size_t)(q0 + part * 32 + srow) * DHEAD + hh * 32 + gc * 8,
            &QP[hh * 4096 + part * 1024 + tid * 8]);
  #pragma unroll
  for (int hh = 0; hh < 2; ++hh)
    #pragma unroll
    for (int part = 0; part < 2; ++part)
      lds16(kbase + (size_t)(part * 32 + srow) * DHEAD + hh * 32 + gc * 8,
            &Ks[hh][part * 1024 + tid * 8]);
  #pragma unroll
  for (int hh = 0; hh < 2; ++hh)
    #pragma unroll
    for (int part = 0; part < 2; ++part)
      lds16(vbase + (size_t)(part * 32 + srow) * SEQ + hh * 32 + gc * 8,
            &Vt[0][hh][part * 1024 + tid * 8]);
  asm volatile("s_waitcnt vmcnt(8)" ::: "memory");  // Q landed; K0/V0 in flight
  __builtin_amdgcn_s_barrier();

  // Q fragments -> registers (loop-invariant).  8 x b128 = 32 VGPRs.
  // Safe vs Ps overwrite: aq is consumed by iter-0 QK (forces lgkm drain)
  // before the post-QK barrier that precedes any Ps write.
  bf16x8 aq[2][4];
  #pragma unroll
  for (int hh = 0; hh < 2; ++hh)
    #pragma unroll
    for (int i = 0; i < 4; ++i)
      aq[hh][i] = *(const bf16x8*)
          &QP[hh * 4096 + (w * 64 + i * 16 + l15) * 32 + (quad ^ sw) * 8];

  float lsum[4][4] = {};
  f32x4 o[4][4] = {};
  int cur = 0;

  for (int it = 0; it < SEQ / 64; ++it) {
    // K(it) landed (oldest 4 of {K(it),V(it)}); publish across waves.
    asm volatile("s_waitcnt vmcnt(4)" ::: "memory");
    __builtin_amdgcn_s_barrier();

    // S = Q K^T (log2-domain), 32 MFMA, 8 Ks reads
    f32x4 s[4][4] = {};
    __builtin_amdgcn_s_setprio(1);
    #pragma unroll
    for (int j = 0; j < 4; ++j)
      #pragma unroll
      for (int hh = 0; hh < 2; ++hh) {
        const bf16x8 bk = *(const bf16x8*)
            &Ks[hh][(j * 16 + l15) * 32 + (quad ^ sw) * 8];
        #pragma unroll
        for (int i = 0; i < 4; ++i)
          s[i][j] = MFMA16(aq[hh][i], bk, s[i][j]);
      }
    __builtin_amdgcn_s_setprio(0);
    __builtin_amdgcn_s_barrier();   // all waves done reading Ks

    // prefetch next tile: all K first, then all V (counted-wait grouping)
    const int tn = ((it + 1) & (SEQ / 64 - 1)) << 6;
    #pragma unroll
    for (int hh = 0; hh < 2; ++hh)
      #pragma unroll
      for (int part = 0; part < 2; ++part)
        lds16(kbase + (size_t)(tn + part * 32 + srow) * DHEAD + hh * 32 + gc * 8,
              &Ks[hh][part * 1024 + tid * 8]);
    #pragma unroll
    for (int hh = 0; hh < 2; ++hh)
      #pragma unroll
      for (int part = 0; part < 2; ++part)
        lds16(vbase + (size_t)(part * 32 + srow) * SEQ + tn + hh * 32 + gc * 8,
              &Vt[cur ^ 1][hh][part * 1024 + tid * 8]);

    // P = exp2(S); per-lane row partials; packed bf16 store into swizzled Ps.
    // content chunk c = l15>>1 at slot c ^ (row&7); key perm p = l15*4+j.
    #pragma unroll
    for (int i = 0; i < 4; ++i)
      #pragma unroll
      for (int r = 0; r < 4; ++r) {
        const float p0 = EXP2F(s[i][0][r]);
        const float p1 = EXP2F(s[i][1][r]);
        const float p2 = EXP2F(s[i][2][r]);
        const float p3 = EXP2F(s[i][3][r]);
        lsum[i][r] += (p0 + p1) + (p2 + p3);
        const int row = w * 64 + i * 16 + (quad << 2) + r;
        const int cs = ((l15 >> 1) ^ (row & 7)) * 8 + (l15 & 1) * 4;
        u32x2 pk;
        pk.x = cvtpk(p0, p1);
        pk.y = cvtpk(p2, p3);
        *(u32x2*)&QP[row * 64 + cs] = pk;
      }
    // Ps rows wave-private: intra-wave LDS write->read ordering is enforced.

    // V(it) landed (oldest 4 of {V(it),K(it+1),V(it+1)}); publish.
    asm volatile("s_waitcnt vmcnt(8)" ::: "memory");
    __builtin_amdgcn_s_barrier();

    // O += P V  (32 MFMA, 8 Ps + 8 Vt reads)
    __builtin_amdgcn_s_setprio(1);
    #pragma unroll
    for (int hh = 0; hh < 2; ++hh) {
      bf16x8 ap[4];
      #pragma unroll
      for (int i = 0; i < 4; ++i) {
        const int row = w * 64 + i * 16 + l15;
        ap[i] = *(const bf16x8*)
            &QP[row * 64 + (((hh * 4 + quad) ^ (row & 7)) << 3)];
      }
      #pragma unroll
      for (int j = 0; j < 4; ++j) {
        const bf16x8 vb = *(const bf16x8*)
            &Vt[cur][hh][(j * 16 + l15) * 32 + (quad ^ sw) * 8];
        #pragma unroll
        for (int i = 0; i < 4; ++i)
          o[i][j] = MFMA16(ap[i], vb, o[i][j]);
      }
    }
    __builtin_amdgcn_s_setprio(0);
    cur ^= 1;
  }
  // drain wrapped-prefetch LDS-DMA before LDS dealloc / endpgm
  asm volatile("s_waitcnt vmcnt(0)" ::: "memory");

  float inv[4][4];
  #pragma unroll
  for (int i = 0; i < 4; ++i)
    #pragma unroll
    for (int r = 0; r < 4; ++r) {
      float t = lsum[i][r];
      #pragma unroll
      for (int off = 1; off < 16; off <<= 1)
        t += __shfl_xor(t, off);
      inv[i][r] = 1.f / t;
    }

  #pragma unroll
  for (int i = 0; i < 4; ++i)
    #pragma unroll
    for (int j = 0; j < 4; ++j)
      #pragma unroll
      for (int r = 0; r < 4; ++r) {
        const int qrow = q0 + w * 64 + i * 16 + (quad << 2) + r;
        Hidden[((size_t)(b * SEQ + qrow)) * HID + h * DHEAD + j * 16 + l15] =
            f2bf(o[i][j][r] * inv[i][r]);
      }
}

extern "C" void kernel_launch(void* const* d_in, const int* in_sizes, int n_in,
                              void* d_out, int out_size, void* d_ws, size_t ws_size,
                              hipStream_t stream) {
  const float* q  = (const float*)d_in[0];
  const float* k  = (const float*)d_in[1];
  const float* v  = (const float*)d_in[2];
  const int* mask = (const int*)d_in[3];
  const float* wq = (const float*)d_in[4];
  const float* bq = (const float*)d_in[5];
  const float* wk = (const float*)d_in[6];
  const float* bk = (const float*)d_in[7];
  const float* wv = (const float*)d_in[8];
  const float* bv = (const float*)d_in[9];
  const float* wo = (const float*)d_in[10];
  const float* bo = (const float*)d_in[11];

  const size_t SEG = (size_t)MROWS * HID;   // 8388608
  const size_t WSEG = (size_t)HID * HID;    // 1048576 = 1<<20
  const dim3 gq(MROWS / 128, HID / 128, 3); // fused QKV: 1536 blocks
  const dim3 go(MROWS / 128, HID / 128);
  const dim3 ga(SEQ / 128, BATCH * HEADS);  // 16 x 64

  const size_t planFULL = (6 * SEG + 4 * WSEG) * sizeof(u16);  // ~104 MB
  const size_t planMID  = (4 * SEG + 4 * WSEG) * sizeof(u16);  // ~75.5 MB

  if (ws_size >= planFULL) {
    // FULL: everything bf16, all GEMM operands on the global_load_lds path.
    u16* qb  = (u16*)d_ws;
    u16* kb  = qb + SEG;
    u16* vb  = kb + SEG;
    u16* qh  = vb + SEG;
    u16* kh  = qh + SEG;
    u16* vt  = kh + SEG;
    u16* wqb = vt + SEG;
    u16* wkb = wqb + WSEG;
    u16* wvb = wkb + WSEG;
    u16* wob = wvb + WSEG;
    u16* hidden = qb;  // alias (qb dead after gemm_qkv)

    CvtArgs ca;
    ca.src[0] = q;  ca.dst[0] = qb;
    ca.src[1] = k;  ca.dst[1] = kb;
    ca.src[2] = v;  ca.dst[2] = vb;
    ca.src[3] = wq; ca.dst[3] = wqb;
    ca.src[4] = wk; ca.dst[4] = wkb;
    ca.src[5] = wv; ca.dst[5] = wvb;
    ca.src[6] = wo; ca.dst[6] = wob;
    cvt7<<<dim3(SEG / 2048, 4), 256, 0, stream>>>(ca, 0, (int)SEG);

    gemm_qkv<true, true><<<gq, 256, 0, stream>>>(qb, kb, vb, wqb, wkb, wvb,
                                                 bq, bk, bv, mask, qh, kh, vt);
    attn_mfma<<<ga, 128, 0, stream>>>(qh, kh, vt, hidden);
    gemm_out<true><<<go, 256, 0, stream>>>(hidden, wob, bo, (float*)d_out);
  } else if (ws_size >= planMID) {
    // MID: weights bf16-DMA, fp32 activations VALU-staged
    u16* wqb = (u16*)d_ws;
    u16* wkb = wqb + WSEG;
    u16* wvb = wkb + WSEG;
    u16* wob = wvb + WSEG;
    u16* qh = wob + WSEG;
    u16* kh = qh + SEG;
    u16* vt = kh + SEG;
    u16* hidden = vt + SEG;

    CvtArgs ca;
    ca.src[0] = ca.src[1] = ca.src[2] = q;  // unused slots
    ca.dst[0] = ca.dst[1] = ca.dst[2] = wqb;
    ca.src[3] = wq; ca.dst[3] = wqb;
    ca.src[4] = wk; ca.dst[4] = wkb;
    ca.src[5] = wv; ca.dst[5] = wvb;
    ca.src[6] = wo; ca.dst[6] = wob;
    cvt7<<<dim3(4 * WSEG / 2048, 1), 256, 0, stream>>>(ca, 3, 0);

    gemm_qkv<false, true><<<gq, 256, 0, stream>>>(q, k, v, wqb, wkb, wvb,
                                                  bq, bk, bv, mask, qh, kh, vt);
    attn_mfma<<<ga, 128, 0, stream>>>(qh, kh, vt, hidden);
    gemm_out<true><<<go, 256, 0, stream>>>(hidden, wob, bo, (float*)d_out);
  } else {
    // LOW: 64 MiB ws, all fp32 operands VALU-staged
    u16* qh = (u16*)d_ws;
    u16* kh = qh + SEG;
    u16* vt = kh + SEG;
    u16* hidden = vt + SEG;

    gemm_qkv<false, false><<<gq, 256, 0, stream>>>(q, k, v, wq, wk, wv,
                                                   bq, bk, bv, mask, qh, kh, vt);
    attn_mfma<<<ga, 128, 0, stream>>>(qh, kh, vt, hidden);
    gemm_out<false><<<go, 256, 0, stream>>>(hidden, wo, bo, (float*)d_out);
  }
}

// Round 2
// 328.906 us; speedup vs baseline: 1.0886x; 1.0428x over previous
//
#include <hip/hip_runtime.h>

#define BATCH 4
#define SEQ 2048
#define HEADS 16
#define DHEAD 64
#define HID 1024
#define MROWS (BATCH * SEQ)   // 8192
#define QSCALE 0.1803368801111092f   // 0.125 * log2(e): exp2 domain

typedef unsigned short u16;
typedef unsigned int u32;
typedef __attribute__((ext_vector_type(4))) float f32x4;
typedef __attribute__((ext_vector_type(8))) short bf16x8;
typedef __attribute__((ext_vector_type(2))) unsigned int u32x2;
typedef __attribute__((ext_vector_type(4))) unsigned int u32x4;

#define MFMA16(a, b, c) __builtin_amdgcn_mfma_f32_16x16x32_bf16((a), (b), (c), 0, 0, 0)
#define EXP2F(x) __builtin_amdgcn_exp2f(x)

// f32 -> bf16 round-to-nearest-even (finite inputs)
__device__ __forceinline__ u16 f2bf(float f) {
  union { float f; u32 i; } x; x.f = f;
  u32 r = x.i + 0x7fffu + ((x.i >> 16) & 1u);
  return (u16)(r >> 16);
}

// packed f32 pair -> bf16 pair (RNE), one VALU op.  No builtin on gfx950 ->
// inline asm (T12 primitive).  D[15:0]=bf16(a), D[31:16]=bf16(b).
__device__ __forceinline__ u32 cvtpk(float a, float b) {
  u32 d;
  asm("v_cvt_pk_bf16_f32 %0, %1, %2" : "=v"(d) : "v"(a), "v"(b));
  return d;
}

// async global->LDS, 16 B/lane.  LDS dest must be wave-uniform base + lane*16.
__device__ __forceinline__ void lds16(const u16* g, u16* s) {
  __builtin_amdgcn_global_load_lds(
      (const __attribute__((address_space(1))) void*)g,
      (__attribute__((address_space(3))) void*)s, 16, 0, 0);
}

// VALU staging: 8 fp32 -> 8 bf16 (fallback paths + cvt kernel)
__device__ __forceinline__ void stage8f(const float* __restrict__ g, u16* s) {
  const float4 a = *(const float4*)g;
  const float4 b = *(const float4*)(g + 4);
  ushort4 lo, hi;
  lo.x = f2bf(a.x); lo.y = f2bf(a.y); lo.z = f2bf(a.z); lo.w = f2bf(a.w);
  hi.x = f2bf(b.x); hi.y = f2bf(b.y); hi.z = f2bf(b.z); hi.w = f2bf(b.w);
  *(ushort4*)s = lo;
  *(ushort4*)(s + 4) = hi;
}

// fp32 -> bf16 for up to 7 tensors in one launch.
// y(+yoff)=0..2: activations (n = SEG).  y=3: the 4 weights, packed as one
// 4*WSEG range (WSEG = 1<<20; j = i>>20 selects the tensor).
struct CvtArgs {
  const float* src[7];
  u16* dst[7];
};
__global__ __launch_bounds__(256) void cvt7(CvtArgs args, int yoff, int nact) {
  const int y = blockIdx.y + yoff;
  const int i = (blockIdx.x * 256 + threadIdx.x) * 8;
  if (y < 3) {
    if (i < nact) stage8f(args.src[y] + i, args.dst[y] + i);
  } else {
    if (i < 4 * (1 << 20)) {
      const int j = i >> 20, off = i & ((1 << 20) - 1);
      stage8f(args.src[3 + j] + off, args.dst[3 + j] + off);
    }
  }
}

// 128x128x(BK=32) MFMA GEMM core: C = A[M,K] @ W[N,K]^T, fp32 accum.
// ADMA/BDMA=1: operand bf16, global_load_lds; =0: fp32, VALU convert-stage.
// LDS chunk-slot XOR swizzle (slot = chunk ^ ((row>>1)&3)) -> conflict-free
// ds_read_b128 fragments while keeping the global_load_lds lane->slot contract.
template<bool ADMA, bool BDMA>
__device__ __forceinline__ void gemm_core(
    const void* __restrict__ Av, const void* __restrict__ Wv,
    int tid, int m0, int n0, u16* As, u16* Bs, f32x4 (&acc)[4][4])
{
  const int srow = tid >> 2, cslot = tid & 3;
  const int gc = cslot ^ ((srow >> 1) & 3);   // swizzled global chunk
  const int w = tid >> 6, l = tid & 63;
  const int quad = l >> 4, l15 = l & 15;
  const int sw = (l15 >> 1) & 3;
  const int wm = (w & 1) << 6, wn = (w >> 1) << 6;

  for (int k0 = 0; k0 < HID; k0 += 32) {
    if (ADMA) {
      const u16* ag = (const u16*)Av + (size_t)(m0 + srow) * HID + k0 + gc * 8;
      lds16(ag, &As[tid * 8]);
      lds16(ag + (size_t)64 * HID, &As[2048 + tid * 8]);
    } else {
      const float* ag = (const float*)Av + (size_t)(m0 + srow) * HID + k0 + gc * 8;
      stage8f(ag, &As[srow * 32 + cslot * 8]);
      stage8f(ag + (size_t)64 * HID, &As[(64 + srow) * 32 + cslot * 8]);
    }
    if (BDMA) {
      const u16* bg = (const u16*)Wv + (size_t)(n0 + srow) * HID + k0 + gc * 8;
      lds16(bg, &Bs[tid * 8]);
      lds16(bg + (size_t)64 * HID, &Bs[2048 + tid * 8]);
    } else {
      const float* bg = (const float*)Wv + (size_t)(n0 + srow) * HID + k0 + gc * 8;
      stage8f(bg, &Bs[srow * 32 + cslot * 8]);
      stage8f(bg + (size_t)64 * HID, &Bs[(64 + srow) * 32 + cslot * 8]);
    }
    __syncthreads();

    bf16x8 a[4], b[4];
    #pragma unroll
    for (int i = 0; i < 4; ++i)
      a[i] = *(const bf16x8*)&As[(wm + i * 16 + l15) * 32 + (quad ^ sw) * 8];
    #pragma unroll
    for (int j = 0; j < 4; ++j)
      b[j] = *(const bf16x8*)&Bs[(wn + j * 16 + l15) * 32 + (quad ^ sw) * 8];
    #pragma unroll
    for (int i = 0; i < 4; ++i)
      #pragma unroll
      for (int j = 0; j < 4; ++j)
        acc[i][j] = MFMA16(a[i], b[j], acc[i][j]);
    __syncthreads();
  }
}

// Fused QKV projection.  blockIdx.z selects q/k/v.  Epilogues:
//  z=0 (Q): *QSCALE and *mask(query row) -> masked rows produce logits 0.
//  z=1 (K): plain bf16 [bh][s][64].
//  z=2 (V): bf16 [bh][d][s], keys PERMUTED within each 64-group
//           (key s0 -> slot (s0&15)*4 + (s0>>4)).  Under this perm, slot
//           group [c*8..c*8+7] (chunk c = quad*2+hh) holds exactly keys
//           {i*16 + quad*4 + (2hh+e>>2)} -- the attention P^T register
//           fragment coverage, so PV's V b128 read needs no shuffle.
template<bool ADMA, bool BDMA>
__global__ __launch_bounds__(256) void gemm_qkv(
    const void* __restrict__ xq, const void* __restrict__ xk,
    const void* __restrict__ xv,
    const void* __restrict__ wqv, const void* __restrict__ wkv,
    const void* __restrict__ wvv,
    const float* __restrict__ bq, const float* __restrict__ bk,
    const float* __restrict__ bv, const int* __restrict__ Mask,
    u16* __restrict__ qh, u16* __restrict__ kh, u16* __restrict__ vt)
{
  __shared__ u16 As[128 * 32];
  __shared__ u16 Bs[128 * 32];
  const int z = blockIdx.z;
  const void* A = (z == 0) ? xq : (z == 1) ? xk : xv;
  const void* W = (z == 0) ? wqv : (z == 1) ? wkv : wvv;
  const float* Bias = (z == 0) ? bq : (z == 1) ? bk : bv;

  const int tid = threadIdx.x;
  const int m0 = blockIdx.x << 7, n0 = blockIdx.y << 7;
  f32x4 acc[4][4] = {};
  gemm_core<ADMA, BDMA>(A, W, tid, m0, n0, As, Bs, acc);

  const int w = tid >> 6, l = tid & 63;
  const int quad = l >> 4, l15 = l & 15;
  const int wm = (w & 1) << 6, wn = (w >> 1) << 6;

  if (z <= 1) {
    u16* Out = (z == 0) ? qh : kh;
    #pragma unroll
    for (int i = 0; i < 4; ++i) {
      float fl[4];
      #pragma unroll
      for (int r = 0; r < 4; ++r) {
        const int m = m0 + wm + i * 16 + (quad << 2) + r;
        fl[r] = (z == 0) ? (Mask[m] ? QSCALE : 0.f) : 1.f;
      }
      #pragma unroll
      for (int j = 0; j < 4; ++j) {
        const int n = n0 + wn + j * 16 + l15;
        const float bias = Bias[n];
        const int h = n >> 6, d = n & 63;
        #pragma unroll
        for (int r = 0; r < 4; ++r) {
          const int m = m0 + wm + i * 16 + (quad << 2) + r;
          const int bb = m >> 11, s = m & (SEQ - 1);
          Out[((size_t)(bb * HEADS + h) * SEQ + s) * DHEAD + d] =
              f2bf((acc[i][j][r] + bias) * fl[r]);
        }
      }
    }
  } else {
    const int sblk = (m0 + wm) & (SEQ - 1);
    const int bb = (m0 + wm) >> 11;
    #pragma unroll
    for (int j = 0; j < 4; ++j) {
      const int n = n0 + wn + j * 16 + l15;
      const float bias = Bias[n];
      const int h = n >> 6, d = n & 63;
      u16* base = vt + ((size_t)(bb * HEADS + h) * DHEAD + d) * SEQ + sblk;
      #pragma unroll
      for (int r = 0; r < 4; ++r) {
        u32x2 pk;
        pk.x = cvtpk(acc[0][j][r] + bias, acc[1][j][r] + bias);
        pk.y = cvtpk(acc[2][j][r] + bias, acc[3][j][r] + bias);
        *(u32x2*)(base + ((quad << 2) + r) * 4) = pk;
      }
    }
  }
}

// Output projection: fp32 out = hidden(bf16) @ wo^T + bo
template<bool BDMA>
__global__ __launch_bounds__(256) void gemm_out(
    const u16* __restrict__ hidden, const void* __restrict__ wov,
    const float* __restrict__ bo, float* __restrict__ Out)
{
  __shared__ u16 As[128 * 32];
  __shared__ u16 Bs[128 * 32];
  const int tid = threadIdx.x;
  const int m0 = blockIdx.x << 7, n0 = blockIdx.y << 7;
  f32x4 acc[4][4] = {};
  gemm_core<true, BDMA>(hidden, wov, tid, m0, n0, As, Bs, acc);

  const int w = tid >> 6, l = tid & 63;
  const int quad = l >> 4, l15 = l & 15;
  const int wm = (w & 1) << 6, wn = (w >> 1) << 6;
  #pragma unroll
  for (int j = 0; j < 4; ++j) {
    const int n = n0 + wn + j * 16 + l15;
    const float bias = bo[n];
    #pragma unroll
    for (int i = 0; i < 4; ++i) {
      const int mb = m0 + wm + i * 16 + (quad << 2);
      #pragma unroll
      for (int r = 0; r < 4; ++r)
        Out[(size_t)(mb + r) * HID + n] = acc[i][j][r] + bias;
    }
  }
}

// Flash attention, no-max softmax, SWAPPED-OPERAND form (zero P LDS traffic).
// 128-thread blocks (2 waves); each wave owns 64 queries x all 64 keys/tile.
//
//  S^T = mfma(K, Q): lane holds P^T[key][query] with query = lane&15 -- the
//  exact B-fragment layout PV needs.  P^T is packed in-register (cvt_pk) and
//  fed straight to O^T = mfma(V^T, P^T); gemm_qkv's V key-permutation makes
//  the per-lane b128 V read cover precisely the 8 keys each P^T fragment
//  holds (r-parity split hh).  Softmax denominator: lacc = mfma(ones, P^T)
//  -- MFMA's k-sum gives every lane the full row sum, no VALU adds and no
//  final shuffle reduce.
//  Per iter per wave: 16 ds_read_b128 total (8 K + 8 V), 72 MFMA, 0 LDS
//  writes -- vs 24 reads + 16 writes in the previous layout.
//
// Pipelined tile loop (T3/T4 counted-vmcnt, raw s_barrier):
//   top:      s_waitcnt vmcnt(4)  -> K(t) landed        ; barrier
//   QK^T      (reads Ks)                                ; barrier
//   issue     K(t+1) -> Ks (4 loads), V(t+1) -> Vt[cur^1] (4 loads)
//   exp2/pack (register-only) ; lacc MFMAs
//   pre-PV:   s_waitcnt vmcnt(8)  -> V(t) landed        ; barrier
//   PV        (reads Vt[cur], bp regs)
// Vt rows are 128 B -> 16B-chunk XOR swizzle slot = c ^ (d&7) (st_16x32 form),
// applied via pre-swizzled global source (global_load_lds dest stays linear).
// LDS 40 KB (Qs 16K + Ks 8K + Vt 2x8K) = 4 blocks/CU; grid-limited anyway.
// XCD remap: bh = lin&63 -> all 16 q-tiles of a head on one XCD's L2.
__global__ __launch_bounds__(128, 2) void attn_mfma(
    const u16* __restrict__ QH, const u16* __restrict__ KH,
    const u16* __restrict__ VT, u16* __restrict__ Hidden)
{
  __shared__ u16 Qs[2][128 * 32];  // 16 KB (dead after prologue)
  __shared__ u16 Ks[2][2048];      // 8 KB, single-buffered (restage post-QK)
  __shared__ u16 Vt[2][4096];      // 16 KB: [buf][64 d][64 key-slots], swizzled

  const int tid = threadIdx.x;     // 0..127
  const int w = tid >> 6, l = tid & 63;
  const int quad = l >> 4, l15 = l & 15;
  const int sw = (l15 >> 1) & 3;
  const int srow = tid >> 2, cslot = tid & 3;
  const int gc = cslot ^ ((srow >> 1) & 3);   // K/Q staging swizzle
  const int vd = tid >> 3;                    // V staging: row within part
  const int vc = (tid & 7) ^ (vd & 7);        // V staging: content chunk

  const int lin = blockIdx.y * 16 + blockIdx.x;
  const int bh = lin & 63, b = bh >> 4, h = bh & 15;
  const int q0 = (lin >> 6) << 7;

  const u16* qbase = QH + (size_t)bh * SEQ * DHEAD;
  const u16* kbase = KH + (size_t)bh * SEQ * DHEAD;
  const u16* vbase = VT + (size_t)bh * DHEAD * SEQ;

  // prologue: Q (8 loads), then K(0) (4), then V(0) (4) -- order matters for
  // the counted waits below.
  #pragma unroll
  for (int hh = 0; hh < 2; ++hh)
    #pragma unroll
    for (int part = 0; part < 4; ++part)
      lds16(qbase + (size_t)(q0 + part * 32 + srow) * DHEAD + hh * 32 + gc * 8,
            &Qs[hh][part * 1024 + tid * 8]);
  #pragma unroll
  for (int hh = 0; hh < 2; ++hh)
    #pragma unroll
    for (int part = 0; part < 2; ++part)
      lds16(kbase + (size_t)(part * 32 + srow) * DHEAD + hh * 32 + gc * 8,
            &Ks[hh][part * 1024 + tid * 8]);
  #pragma unroll
  for (int part = 0; part < 4; ++part)
    lds16(vbase + (size_t)(part * 16 + vd) * SEQ + vc * 8,
          &Vt[0][part * 1024 + tid * 8]);
  asm volatile("s_waitcnt vmcnt(8)" ::: "memory");  // Q landed; K0/V0 in flight
  __builtin_amdgcn_s_barrier();

  // Q fragments -> registers (loop-invariant, B-operand).  32 VGPRs.
  bf16x8 aq[2][4];
  #pragma unroll
  for (int hh = 0; hh < 2; ++hh)
    #pragma unroll
    for (int j = 0; j < 4; ++j)
      aq[hh][j] = *(const bf16x8*)
          &Qs[hh][(w * 64 + j * 16 + l15) * 32 + (quad ^ sw) * 8];

  const bf16x8 ones8 = {0x3F80, 0x3F80, 0x3F80, 0x3F80,
                        0x3F80, 0x3F80, 0x3F80, 0x3F80};  // bf16 1.0 x8
  f32x4 o[4][4] = {};      // O^T accum: [d-tile][q-tile]
  f32x4 lacc[4] = {};      // denominator accum per q-tile (rows all equal)
  int cur = 0;

  for (int it = 0; it < SEQ / 64; ++it) {
    // K(it) landed (oldest 4 of {K(it),V(it)}); publish across waves.
    asm volatile("s_waitcnt vmcnt(4)" ::: "memory");
    __builtin_amdgcn_s_barrier();

    // S^T = K Q^T (log2-domain): 32 MFMA, 8 Ks reads.  i = key tile,
    // j = query tile; lane: col = query l15, rows = keys quad*4+r.
    f32x4 s[4][4] = {};
    __builtin_amdgcn_s_setprio(1);
    #pragma unroll
    for (int i = 0; i < 4; ++i)
      #pragma unroll
      for (int hh = 0; hh < 2; ++hh) {
        const bf16x8 ak = *(const bf16x8*)
            &Ks[hh][(i * 16 + l15) * 32 + (quad ^ sw) * 8];
        #pragma unroll
        for (int j = 0; j < 4; ++j)
          s[i][j] = MFMA16(ak, aq[hh][j], s[i][j]);
      }
    __builtin_amdgcn_s_setprio(0);
    __builtin_amdgcn_s_barrier();   // all waves done reading Ks

    // prefetch next tile: all K first, then all V (counted-wait grouping)
    const int tn = ((it + 1) & (SEQ / 64 - 1)) << 6;
    #pragma unroll
    for (int hh = 0; hh < 2; ++hh)
      #pragma unroll
      for (int part = 0; part < 2; ++part)
        lds16(kbase + (size_t)(tn + part * 32 + srow) * DHEAD + hh * 32 + gc * 8,
              &Ks[hh][part * 1024 + tid * 8]);
    #pragma unroll
    for (int part = 0; part < 4; ++part)
      lds16(vbase + (size_t)(part * 16 + vd) * SEQ + tn + vc * 8,
            &Vt[cur ^ 1][part * 1024 + tid * 8]);

    // P^T = exp2(S^T), packed in-register to PV B-fragments.
    // bp[hh][j] element e <-> key (e&3)*16 + quad*4 + 2hh + (e>>2), matching
    // the V slot-permutation.  Denominator via mfma(ones, bp): k-sum gives
    // every lane the full 64-key partial for query l15.
    bf16x8 bp[2][4];
    #pragma unroll
    for (int j = 0; j < 4; ++j) {
      float p[4][4];
      #pragma unroll
      for (int i = 0; i < 4; ++i)
        #pragma unroll
        for (int r = 0; r < 4; ++r)
          p[i][r] = EXP2F(s[i][j][r]);
      u32x4 t0, t1;
      t0.x = cvtpk(p[0][0], p[1][0]); t0.y = cvtpk(p[2][0], p[3][0]);
      t0.z = cvtpk(p[0][1], p[1][1]); t0.w = cvtpk(p[2][1], p[3][1]);
      t1.x = cvtpk(p[0][2], p[1][2]); t1.y = cvtpk(p[2][2], p[3][2]);
      t1.z = cvtpk(p[0][3], p[1][3]); t1.w = cvtpk(p[2][3], p[3][3]);
      bp[0][j] = __builtin_bit_cast(bf16x8, t0);
      bp[1][j] = __builtin_bit_cast(bf16x8, t1);
      lacc[j] = MFMA16(ones8, bp[0][j], lacc[j]);
      lacc[j] = MFMA16(ones8, bp[1][j], lacc[j]);
    }

    // V(it) landed (oldest 4 of {V(it),K(it+1),V(it+1)}); publish.
    asm volatile("s_waitcnt vmcnt(8)" ::: "memory");
    __builtin_amdgcn_s_barrier();

    // O^T += V^T P^T  (32 MFMA, 8 Vt b128 reads, bp from registers)
    __builtin_amdgcn_s_setprio(1);
    #pragma unroll
    for (int hh = 0; hh < 2; ++hh)
      #pragma unroll
      for (int m = 0; m < 4; ++m) {
        const int d = m * 16 + l15;
        const bf16x8 av = *(const bf16x8*)
            &Vt[cur][d * 64 + (((quad * 2 + hh) ^ (d & 7)) << 3)];
        #pragma unroll
        for (int j = 0; j < 4; ++j)
          o[m][j] = MFMA16(av, bp[hh][j], o[m][j]);
      }
    __builtin_amdgcn_s_setprio(0);
    cur ^= 1;
  }
  // drain wrapped-prefetch LDS-DMA before LDS dealloc / endpgm
  asm volatile("s_waitcnt vmcnt(0)" ::: "memory");

  // denominator: every lane already holds the full sum for query l15
  float inv[4];
  #pragma unroll
  for (int j = 0; j < 4; ++j)
    inv[j] = 1.f / lacc[j][0];

  // O^T lane layout: query = j*16 + l15 (row), d = m*16 + quad*4 + r (col)
  // -> 4 contiguous bf16 per (m,j): one 8 B store.
  #pragma unroll
  for (int m = 0; m < 4; ++m)
    #pragma unroll
    for (int j = 0; j < 4; ++j) {
      u32x2 pk;
      pk.x = cvtpk(o[m][j][0] * inv[j], o[m][j][1] * inv[j]);
      pk.y = cvtpk(o[m][j][2] * inv[j], o[m][j][3] * inv[j]);
      *(u32x2*)&Hidden[(size_t)(b * SEQ + q0 + w * 64 + j * 16 + l15) * HID
                       + h * DHEAD + m * 16 + quad * 4] = pk;
    }
}

extern "C" void kernel_launch(void* const* d_in, const int* in_sizes, int n_in,
                              void* d_out, int out_size, void* d_ws, size_t ws_size,
                              hipStream_t stream) {
  const float* q  = (const float*)d_in[0];
  const float* k  = (const float*)d_in[1];
  const float* v  = (const float*)d_in[2];
  const int* mask = (const int*)d_in[3];
  const float* wq = (const float*)d_in[4];
  const float* bq = (const float*)d_in[5];
  const float* wk = (const float*)d_in[6];
  const float* bk = (const float*)d_in[7];
  const float* wv = (const float*)d_in[8];
  const float* bv = (const float*)d_in[9];
  const float* wo = (const float*)d_in[10];
  const float* bo = (const float*)d_in[11];

  const size_t SEG = (size_t)MROWS * HID;   // 8388608
  const size_t WSEG = (size_t)HID * HID;    // 1048576 = 1<<20
  const dim3 gq(MROWS / 128, HID / 128, 3); // fused QKV: 1536 blocks
  const dim3 go(MROWS / 128, HID / 128);
  const dim3 ga(SEQ / 128, BATCH * HEADS);  // 16 x 64

  const size_t planFULL = (6 * SEG + 4 * WSEG) * sizeof(u16);  // ~104 MB
  const size_t planMID  = (4 * SEG + 4 * WSEG) * sizeof(u16);  // ~75.5 MB

  if (ws_size >= planFULL) {
    // FULL: everything bf16, all GEMM operands on the global_load_lds path.
    u16* qb  = (u16*)d_ws;
    u16* kb  = qb + SEG;
    u16* vb  = kb + SEG;
    u16* qh  = vb + SEG;
    u16* kh  = qh + SEG;
    u16* vt  = kh + SEG;
    u16* wqb = vt + SEG;
    u16* wkb = wqb + WSEG;
    u16* wvb = wkb + WSEG;
    u16* wob = wvb + WSEG;
    u16* hidden = qb;  // alias (qb dead after gemm_qkv)

    CvtArgs ca;
    ca.src[0] = q;  ca.dst[0] = qb;
    ca.src[1] = k;  ca.dst[1] = kb;
    ca.src[2] = v;  ca.dst[2] = vb;
    ca.src[3] = wq; ca.dst[3] = wqb;
    ca.src[4] = wk; ca.dst[4] = wkb;
    ca.src[5] = wv; ca.dst[5] = wvb;
    ca.src[6] = wo; ca.dst[6] = wob;
    cvt7<<<dim3(SEG / 2048, 4), 256, 0, stream>>>(ca, 0, (int)SEG);

    gemm_qkv<true, true><<<gq, 256, 0, stream>>>(qb, kb, vb, wqb, wkb, wvb,
                                                 bq, bk, bv, mask, qh, kh, vt);
    attn_mfma<<<ga, 128, 0, stream>>>(qh, kh, vt, hidden);
    gemm_out<true><<<go, 256, 0, stream>>>(hidden, wob, bo, (float*)d_out);
  } else if (ws_size >= planMID) {
    // MID: weights bf16-DMA, fp32 activations VALU-staged
    u16* wqb = (u16*)d_ws;
    u16* wkb = wqb + WSEG;
    u16* wvb = wkb + WSEG;
    u16* wob = wvb + WSEG;
    u16* qh = wob + WSEG;
    u16* kh = qh + SEG;
    u16* vt = kh + SEG;
    u16* hidden = vt + SEG;

    CvtArgs ca;
    ca.src[0] = ca.src[1] = ca.src[2] = q;  // unused slots
    ca.dst[0] = ca.dst[1] = ca.dst[2] = wqb;
    ca.src[3] = wq; ca.dst[3] = wqb;
    ca.src[4] = wk; ca.dst[4] = wkb;
    ca.src[5] = wv; ca.dst[5] = wvb;
    ca.src[6] = wo; ca.dst[6] = wob;
    cvt7<<<dim3(4 * WSEG / 2048, 1), 256, 0, stream>>>(ca, 3, 0);

    gemm_qkv<false, true><<<gq, 256, 0, stream>>>(q, k, v, wqb, wkb, wvb,
                                                  bq, bk, bv, mask, qh, kh, vt);
    attn_mfma<<<ga, 128, 0, stream>>>(qh, kh, vt, hidden);
    gemm_out<true><<<go, 256, 0, stream>>>(hidden, wob, bo, (float*)d_out);
  } else {
    // LOW: 64 MiB ws, all fp32 operands VALU-staged
    u16* qh = (u16*)d_ws;
    u16* kh = qh + SEG;
    u16* vt = kh + SEG;
    u16* hidden = vt + SEG;

    gemm_qkv<false, false><<<gq, 256, 0, stream>>>(q, k, v, wq, wk, wv,
                                                   bq, bk, bv, mask, qh, kh, vt);
    attn_mfma<<<ga, 128, 0, stream>>>(qh, kh, vt, hidden);
    gemm_out<false><<<go, 256, 0, stream>>>(hidden, wo, bo, (float*)d_out);
  }
}

// Round 4
// 322.336 us; speedup vs baseline: 1.1108x; 1.0204x over previous
//
#include <hip/hip_runtime.h>

#define BATCH 4
#define SEQ 2048
#define HEADS 16
#define DHEAD 64
#define HID 1024
#define MROWS (BATCH * SEQ)   // 8192
#define QSCALE 0.1803368801111092f   // 0.125 * log2(e): exp2 domain

typedef unsigned short u16;
typedef unsigned int u32;
typedef __attribute__((ext_vector_type(4))) float f32x4;
typedef __attribute__((ext_vector_type(8))) short bf16x8;
typedef __attribute__((ext_vector_type(2))) unsigned int u32x2;
typedef __attribute__((ext_vector_type(4))) unsigned int u32x4;

#define MFMA16(a, b, c) __builtin_amdgcn_mfma_f32_16x16x32_bf16((a), (b), (c), 0, 0, 0)
#define EXP2F(x) __builtin_amdgcn_exp2f(x)

// f32 -> bf16 round-to-nearest-even (finite inputs)
__device__ __forceinline__ u16 f2bf(float f) {
  union { float f; u32 i; } x; x.f = f;
  u32 r = x.i + 0x7fffu + ((x.i >> 16) & 1u);
  return (u16)(r >> 16);
}

// packed f32 pair -> bf16 pair (RNE), one VALU op (T12 primitive).
__device__ __forceinline__ u32 cvtpk(float a, float b) {
  u32 d;
  asm("v_cvt_pk_bf16_f32 %0, %1, %2" : "=v"(d) : "v"(a), "v"(b));
  return d;
}

// async global->LDS, 16 B/lane.  LDS dest must be wave-uniform base + lane*16.
__device__ __forceinline__ void lds16(const u16* g, u16* s) {
  __builtin_amdgcn_global_load_lds(
      (const __attribute__((address_space(1))) void*)g,
      (__attribute__((address_space(3))) void*)s, 16, 0, 0);
}

// VALU staging: 8 fp32 -> 8 bf16 (fallback paths + cvt kernel)
__device__ __forceinline__ void stage8f(const float* __restrict__ g, u16* s) {
  const float4 a = *(const float4*)g;
  const float4 b = *(const float4*)(g + 4);
  ushort4 lo, hi;
  lo.x = f2bf(a.x); lo.y = f2bf(a.y); lo.z = f2bf(a.z); lo.w = f2bf(a.w);
  hi.x = f2bf(b.x); hi.y = f2bf(b.y); hi.z = f2bf(b.z); hi.w = f2bf(b.w);
  *(ushort4*)s = lo;
  *(ushort4*)(s + 4) = hi;
}

// fp32 -> bf16 for up to 7 tensors in one launch.
struct CvtArgs {
  const float* src[7];
  u16* dst[7];
};
__global__ __launch_bounds__(256) void cvt7(CvtArgs args, int yoff, int nact) {
  const int y = blockIdx.y + yoff;
  const int i = (blockIdx.x * 256 + threadIdx.x) * 8;
  if (y < 3) {
    if (i < nact) stage8f(args.src[y] + i, args.dst[y] + i);
  } else {
    if (i < 4 * (1 << 20)) {
      const int j = i >> 20, off = i & ((1 << 20) - 1);
      stage8f(args.src[3 + j] + off, args.dst[3 + j] + off);
    }
  }
}

// ---------------------------------------------------------------------------
// OLD 128x128x(BK=32) core -- kept for the MID/LOW fallback paths only.
// ---------------------------------------------------------------------------
template<bool ADMA, bool BDMA>
__device__ __forceinline__ void gemm_core(
    const void* __restrict__ Av, const void* __restrict__ Wv,
    int tid, int m0, int n0, u16* As, u16* Bs, f32x4 (&acc)[4][4])
{
  const int srow = tid >> 2, cslot = tid & 3;
  const int gc = cslot ^ ((srow >> 1) & 3);   // swizzled global chunk
  const int w = tid >> 6, l = tid & 63;
  const int quad = l >> 4, l15 = l & 15;
  const int sw = (l15 >> 1) & 3;
  const int wm = (w & 1) << 6, wn = (w >> 1) << 6;

  for (int k0 = 0; k0 < HID; k0 += 32) {
    if (ADMA) {
      const u16* ag = (const u16*)Av + (size_t)(m0 + srow) * HID + k0 + gc * 8;
      lds16(ag, &As[tid * 8]);
      lds16(ag + (size_t)64 * HID, &As[2048 + tid * 8]);
    } else {
      const float* ag = (const float*)Av + (size_t)(m0 + srow) * HID + k0 + gc * 8;
      stage8f(ag, &As[srow * 32 + cslot * 8]);
      stage8f(ag + (size_t)64 * HID, &As[(64 + srow) * 32 + cslot * 8]);
    }
    if (BDMA) {
      const u16* bg = (const u16*)Wv + (size_t)(n0 + srow) * HID + k0 + gc * 8;
      lds16(bg, &Bs[tid * 8]);
      lds16(bg + (size_t)64 * HID, &Bs[2048 + tid * 8]);
    } else {
      const float* bg = (const float*)Wv + (size_t)(n0 + srow) * HID + k0 + gc * 8;
      stage8f(bg, &Bs[srow * 32 + cslot * 8]);
      stage8f(bg + (size_t)64 * HID, &Bs[(64 + srow) * 32 + cslot * 8]);
    }
    __syncthreads();

    bf16x8 a[4], b[4];
    #pragma unroll
    for (int i = 0; i < 4; ++i)
      a[i] = *(const bf16x8*)&As[(wm + i * 16 + l15) * 32 + (quad ^ sw) * 8];
    #pragma unroll
    for (int j = 0; j < 4; ++j)
      b[j] = *(const bf16x8*)&Bs[(wn + j * 16 + l15) * 32 + (quad ^ sw) * 8];
    #pragma unroll
    for (int i = 0; i < 4; ++i)
      #pragma unroll
      for (int j = 0; j < 4; ++j)
        acc[i][j] = MFMA16(a[i], b[j], acc[i][j]);
    __syncthreads();
  }
}

// Fallback fused QKV (MID/LOW).  Epilogue semantics documented at gemm_qkv2.
template<bool ADMA, bool BDMA>
__global__ __launch_bounds__(256) void gemm_qkv(
    const void* __restrict__ xq, const void* __restrict__ xk,
    const void* __restrict__ xv,
    const void* __restrict__ wqv, const void* __restrict__ wkv,
    const void* __restrict__ wvv,
    const float* __restrict__ bq, const float* __restrict__ bk,
    const float* __restrict__ bv, const int* __restrict__ Mask,
    u16* __restrict__ qh, u16* __restrict__ kh, u16* __restrict__ vt)
{
  __shared__ u16 As[128 * 32];
  __shared__ u16 Bs[128 * 32];
  const int z = blockIdx.z;
  const void* A = (z == 0) ? xq : (z == 1) ? xk : xv;
  const void* W = (z == 0) ? wqv : (z == 1) ? wkv : wvv;
  const float* Bias = (z == 0) ? bq : (z == 1) ? bk : bv;

  const int tid = threadIdx.x;
  const int m0 = blockIdx.x << 7, n0 = blockIdx.y << 7;
  f32x4 acc[4][4] = {};
  gemm_core<ADMA, BDMA>(A, W, tid, m0, n0, As, Bs, acc);

  const int w = tid >> 6, l = tid & 63;
  const int quad = l >> 4, l15 = l & 15;
  const int wm = (w & 1) << 6, wn = (w >> 1) << 6;

  if (z <= 1) {
    u16* Out = (z == 0) ? qh : kh;
    #pragma unroll
    for (int i = 0; i < 4; ++i) {
      float fl[4];
      #pragma unroll
      for (int r = 0; r < 4; ++r) {
        const int m = m0 + wm + i * 16 + (quad << 2) + r;
        fl[r] = (z == 0) ? (Mask[m] ? QSCALE : 0.f) : 1.f;
      }
      #pragma unroll
      for (int j = 0; j < 4; ++j) {
        const int n = n0 + wn + j * 16 + l15;
        const float bias = Bias[n];
        const int h = n >> 6, d = n & 63;
        #pragma unroll
        for (int r = 0; r < 4; ++r) {
          const int m = m0 + wm + i * 16 + (quad << 2) + r;
          const int bb = m >> 11, s = m & (SEQ - 1);
          Out[((size_t)(bb * HEADS + h) * SEQ + s) * DHEAD + d] =
              f2bf((acc[i][j][r] + bias) * fl[r]);
        }
      }
    }
  } else {
    const int sblk = (m0 + wm) & (SEQ - 1);
    const int bb = (m0 + wm) >> 11;
    #pragma unroll
    for (int j = 0; j < 4; ++j) {
      const int n = n0 + wn + j * 16 + l15;
      const float bias = Bias[n];
      const int h = n >> 6, d = n & 63;
      u16* base = vt + ((size_t)(bb * HEADS + h) * DHEAD + d) * SEQ + sblk;
      #pragma unroll
      for (int r = 0; r < 4; ++r) {
        u32x2 pk;
        pk.x = cvtpk(acc[0][j][r] + bias, acc[1][j][r] + bias);
        pk.y = cvtpk(acc[2][j][r] + bias, acc[3][j][r] + bias);
        *(u32x2*)(base + ((quad << 2) + r) * 4) = pk;
      }
    }
  }
}

// Fallback output projection (MID/LOW)
template<bool BDMA>
__global__ __launch_bounds__(256) void gemm_out(
    const u16* __restrict__ hidden, const void* __restrict__ wov,
    const float* __restrict__ bo, float* __restrict__ Out)
{
  __shared__ u16 As[128 * 32];
  __shared__ u16 Bs[128 * 32];
  const int tid = threadIdx.x;
  const int m0 = blockIdx.x << 7, n0 = blockIdx.y << 7;
  f32x4 acc[4][4] = {};
  gemm_core<true, BDMA>(hidden, wov, tid, m0, n0, As, Bs, acc);

  const int w = tid >> 6, l = tid & 63;
  const int quad = l >> 4, l15 = l & 15;
  const int wm = (w & 1) << 6, wn = (w >> 1) << 6;
  #pragma unroll
  for (int j = 0; j < 4; ++j) {
    const int n = n0 + wn + j * 16 + l15;
    const float bias = bo[n];
    #pragma unroll
    for (int i = 0; i < 4; ++i) {
      const int mb = m0 + wm + i * 16 + (quad << 2);
      #pragma unroll
      for (int r = 0; r < 4; ++r)
        Out[(size_t)(mb + r) * HID + n] = acc[i][j][r] + bias;
    }
  }
}

// ---------------------------------------------------------------------------
// Pipelined 256x128x(BK=64) core (FULL path).  512 thr = 8 waves (4M x 2N),
// wave tile 64x64 (acc 4x4 f32x4).  Double-buffered LDS (96 KB), 1-deep
// prefetch:
//   iter t:  vmcnt(0)        -- tile t (staged at t-1) landed; ONE stall/iter,
//            barrier          hidden under iter t-1's 64 MFMA + 24 ds_read
//            issue stage(t+1 -> other buffer)  (6 global_load_lds)
//            ks=0,1: 12 ds_read_b128 + 32 MFMA (setprio-wrapped)
// No __syncthreads in the loop (raw s_barrier).  WAR on the double buffer is
// safe: a wave's ds_reads of buffer c must retire (lgkmcnt) before its iter-t
// MFMAs issue, hence before it reaches the iter-t+1 barrier; stage into c
// happens only after that barrier.  LDS rows are 128 B -> 8-slot XOR swizzle
// slot = chunk ^ (row&7), applied on BOTH sides: pre-swizzled global source
// for global_load_lds (linear dest) + swizzled ds_read address.  Balanced
// 8 lanes / 4-bank group (b128 conflict floor).
// ---------------------------------------------------------------------------
__device__ __forceinline__ void core256(
    const u16* __restrict__ A, const u16* __restrict__ W,
    int tid, int m0, int n0, u16* As2, u16* Bs2, f32x4 (&acc)[4][4])
{
  const int l = tid & 63;
  const int quad = l >> 4, l15 = l & 15;
  const int sw7 = l15 & 7;
  const int w = tid >> 6;
  const int wm = (w & 3) << 6, wn = (w >> 2) << 6;
  const int srow = tid >> 3, sslot = tid & 7;   // staging: row-in-part, slot
  const int sgc = sslot ^ (srow & 7);           // content chunk (global side)

  const u16* aB = A + (size_t)(m0 + srow) * HID + sgc * 8;
  const u16* bB = W + (size_t)(n0 + srow) * HID + sgc * 8;

  // prologue: tile 0 -> buffer 0
  #pragma unroll
  for (int p = 0; p < 4; ++p)
    lds16(aB + (size_t)p * 64 * HID, As2 + p * 4096 + tid * 8);
  #pragma unroll
  for (int p = 0; p < 2; ++p)
    lds16(bB + (size_t)p * 64 * HID, Bs2 + p * 4096 + tid * 8);

  #pragma unroll 2
  for (int t = 0; t < HID / 64; ++t) {
    const int c = t & 1;
    asm volatile("s_waitcnt vmcnt(0)" ::: "memory");  // tile t landed
    __builtin_amdgcn_s_barrier();                     // publish + reads-done
    __builtin_amdgcn_sched_barrier(0);

    if (t < HID / 64 - 1) {   // stage tile t+1 into the other buffer
      const int kk = (t + 1) << 6;
      u16* ad = As2 + (c ^ 1) * 16384;
      u16* bd = Bs2 + (c ^ 1) * 8192;
      #pragma unroll
      for (int p = 0; p < 4; ++p)
        lds16(aB + (size_t)p * 64 * HID + kk, ad + p * 4096 + tid * 8);
      #pragma unroll
      for (int p = 0; p < 2; ++p)
        lds16(bB + (size_t)p * 64 * HID + kk, bd + p * 4096 + tid * 8);
    }

    const u16* Ab = As2 + c * 16384;
    const u16* Bb = Bs2 + c * 8192;
    #pragma unroll
    for (int ks = 0; ks < 2; ++ks) {
      const int cc = ((ks << 2) | quad) ^ sw7;
      bf16x8 a[4], b[4];
      #pragma unroll
      for (int i = 0; i < 4; ++i)
        a[i] = *(const bf16x8*)&Ab[(wm + i * 16 + l15) * 64 + cc * 8];
      #pragma unroll
      for (int j = 0; j < 4; ++j)
        b[j] = *(const bf16x8*)&Bb[(wn + j * 16 + l15) * 64 + cc * 8];
      __builtin_amdgcn_s_setprio(1);
      #pragma unroll
      for (int i = 0; i < 4; ++i)
        #pragma unroll
        for (int j = 0; j < 4; ++j)
          acc[i][j] = MFMA16(a[i], b[j], acc[i][j]);
      __builtin_amdgcn_s_setprio(0);
    }
  }
  asm volatile("s_waitcnt vmcnt(0)" ::: "memory");  // drain before LDS death
}

// Fused QKV projection, pipelined core.  768 blocks = 3 exact rounds at
// 1 block/CU.  XCD-chunked bijective remap: nid = (lin&7)*96 + lin>>3, so
// each XCD's L2 sees consecutive n-tiles of the same 512 KB A-panel.
// Epilogues identical to the fallback (z=0 mask*QSCALE; z=2 V^T key-perm).
__global__ __launch_bounds__(512, 1) void gemm_qkv2(
    const u16* __restrict__ xq, const u16* __restrict__ xk,
    const u16* __restrict__ xv,
    const u16* __restrict__ wqv, const u16* __restrict__ wkv,
    const u16* __restrict__ wvv,
    const float* __restrict__ bq, const float* __restrict__ bk,
    const float* __restrict__ bv, const int* __restrict__ Mask,
    u16* __restrict__ qh, u16* __restrict__ kh, u16* __restrict__ vt)
{
  __shared__ u16 As2[2 * 16384];  // 64 KB
  __shared__ u16 Bs2[2 * 8192];   // 32 KB
  const int tid = threadIdx.x;

  const int lin = blockIdx.x;
  const int nid = (lin & 7) * 96 + (lin >> 3);
  const int z = nid >> 8;
  const int rem = nid & 255;
  const int m0 = (rem >> 3) << 8, n0 = (rem & 7) << 7;

  const u16* A = (z == 0) ? xq : (z == 1) ? xk : xv;
  const u16* W = (z == 0) ? wqv : (z == 1) ? wkv : wvv;
  const float* Bias = (z == 0) ? bq : (z == 1) ? bk : bv;

  f32x4 acc[4][4] = {};
  core256(A, W, tid, m0, n0, As2, Bs2, acc);

  const int w = tid >> 6, l = tid & 63;
  const int quad = l >> 4, l15 = l & 15;
  const int wm = (w & 3) << 6, wn = (w >> 2) << 6;

  if (z <= 1) {
    u16* Out = (z == 0) ? qh : kh;
    #pragma unroll
    for (int i = 0; i < 4; ++i) {
      float fl[4];
      #pragma unroll
      for (int r = 0; r < 4; ++r) {
        const int m = m0 + wm + i * 16 + (quad << 2) + r;
        fl[r] = (z == 0) ? (Mask[m] ? QSCALE : 0.f) : 1.f;
      }
      #pragma unroll
      for (int j = 0; j < 4; ++j) {
        const int n = n0 + wn + j * 16 + l15;
        const float bias = Bias[n];
        const int h = n >> 6, d = n & 63;
        #pragma unroll
        for (int r = 0; r < 4; ++r) {
          const int m = m0 + wm + i * 16 + (quad << 2) + r;
          const int bb = m >> 11, s = m & (SEQ - 1);
          Out[((size_t)(bb * HEADS + h) * SEQ + s) * DHEAD + d] =
              f2bf((acc[i][j][r] + bias) * fl[r]);
        }
      }
    }
  } else {
    const int sblk = (m0 + wm) & (SEQ - 1);
    const int bb = (m0 + wm) >> 11;
    #pragma unroll
    for (int j = 0; j < 4; ++j) {
      const int n = n0 + wn + j * 16 + l15;
      const float bias = Bias[n];
      const int h = n >> 6, d = n & 63;
      u16* base = vt + ((size_t)(bb * HEADS + h) * DHEAD + d) * SEQ + sblk;
      #pragma unroll
      for (int r = 0; r < 4; ++r) {
        u32x2 pk;
        pk.x = cvtpk(acc[0][j][r] + bias, acc[1][j][r] + bias);
        pk.y = cvtpk(acc[2][j][r] + bias, acc[3][j][r] + bias);
        *(u32x2*)(base + ((quad << 2) + r) * 4) = pk;
      }
    }
  }
}

// Output projection, pipelined core.  256 blocks = 1 exact round.
__global__ __launch_bounds__(512, 1) void gemm_out2(
    const u16* __restrict__ hidden, const u16* __restrict__ wov,
    const float* __restrict__ bo, float* __restrict__ Out)
{
  __shared__ u16 As2[2 * 16384];
  __shared__ u16 Bs2[2 * 8192];
  const int tid = threadIdx.x;

  const int lin = blockIdx.x;
  const int nid = (lin & 7) * 32 + (lin >> 3);
  const int m0 = (nid >> 3) << 8, n0 = (nid & 7) << 7;

  f32x4 acc[4][4] = {};
  core256(hidden, wov, tid, m0, n0, As2, Bs2, acc);

  const int w = tid >> 6, l = tid & 63;
  const int quad = l >> 4, l15 = l & 15;
  const int wm = (w & 3) << 6, wn = (w >> 2) << 6;
  #pragma unroll
  for (int j = 0; j < 4; ++j) {
    const int n = n0 + wn + j * 16 + l15;
    const float bias = bo[n];
    #pragma unroll
    for (int i = 0; i < 4; ++i) {
      const int mb = m0 + wm + i * 16 + (quad << 2);
      #pragma unroll
      for (int r = 0; r < 4; ++r)
        Out[(size_t)(mb + r) * HID + n] = acc[i][j][r] + bias;
    }
  }
}

// Flash attention, no-max softmax, SWAPPED-OPERAND form (zero P LDS traffic).
// S^T = mfma(K,Q); P^T packed in-register feeds O^T = mfma(V^T, P^T);
// denominator via mfma(ones, P^T).  Counted-vmcnt pipeline, raw barriers.
__global__ __launch_bounds__(128, 2) void attn_mfma(
    const u16* __restrict__ QH, const u16* __restrict__ KH,
    const u16* __restrict__ VT, u16* __restrict__ Hidden)
{
  __shared__ u16 Qs[2][128 * 32];  // 16 KB (dead after prologue)
  __shared__ u16 Ks[2][2048];      // 8 KB, single-buffered (restage post-QK)
  __shared__ u16 Vt[2][4096];      // 16 KB: [buf][64 d][64 key-slots], swizzled

  const int tid = threadIdx.x;     // 0..127
  const int w = tid >> 6, l = tid & 63;
  const int quad = l >> 4, l15 = l & 15;
  const int sw = (l15 >> 1) & 3;
  const int srow = tid >> 2, cslot = tid & 3;
  const int gc = cslot ^ ((srow >> 1) & 3);   // K/Q staging swizzle
  const int vd = tid >> 3;                    // V staging: row within part
  const int vc = (tid & 7) ^ (vd & 7);        // V staging: content chunk

  const int lin = blockIdx.y * 16 + blockIdx.x;
  const int bh = lin & 63, b = bh >> 4, h = bh & 15;
  const int q0 = (lin >> 6) << 7;

  const u16* qbase = QH + (size_t)bh * SEQ * DHEAD;
  const u16* kbase = KH + (size_t)bh * SEQ * DHEAD;
  const u16* vbase = VT + (size_t)bh * DHEAD * SEQ;

  #pragma unroll
  for (int hh = 0; hh < 2; ++hh)
    #pragma unroll
    for (int part = 0; part < 4; ++part)
      lds16(qbase + (size_t)(q0 + part * 32 + srow) * DHEAD + hh * 32 + gc * 8,
            &Qs[hh][part * 1024 + tid * 8]);
  #pragma unroll
  for (int hh = 0; hh < 2; ++hh)
    #pragma unroll
    for (int part = 0; part < 2; ++part)
      lds16(kbase + (size_t)(part * 32 + srow) * DHEAD + hh * 32 + gc * 8,
            &Ks[hh][part * 1024 + tid * 8]);
  #pragma unroll
  for (int part = 0; part < 4; ++part)
    lds16(vbase + (size_t)(part * 16 + vd) * SEQ + vc * 8,
          &Vt[0][part * 1024 + tid * 8]);
  asm volatile("s_waitcnt vmcnt(8)" ::: "memory");  // Q landed; K0/V0 in flight
  __builtin_amdgcn_s_barrier();

  bf16x8 aq[2][4];
  #pragma unroll
  for (int hh = 0; hh < 2; ++hh)
    #pragma unroll
    for (int j = 0; j < 4; ++j)
      aq[hh][j] = *(const bf16x8*)
          &Qs[hh][(w * 64 + j * 16 + l15) * 32 + (quad ^ sw) * 8];

  const bf16x8 ones8 = {0x3F80, 0x3F80, 0x3F80, 0x3F80,
                        0x3F80, 0x3F80, 0x3F80, 0x3F80};  // bf16 1.0 x8
  f32x4 o[4][4] = {};      // O^T accum: [d-tile][q-tile]
  f32x4 lacc[4] = {};      // denominator accum per q-tile
  int cur = 0;

  for (int it = 0; it < SEQ / 64; ++it) {
    asm volatile("s_waitcnt vmcnt(4)" ::: "memory");
    __builtin_amdgcn_s_barrier();

    // S^T = K Q^T (log2-domain): 32 MFMA, 8 Ks reads
    f32x4 s[4][4] = {};
    __builtin_amdgcn_s_setprio(1);
    #pragma unroll
    for (int i = 0; i < 4; ++i)
      #pragma unroll
      for (int hh = 0; hh < 2; ++hh) {
        const bf16x8 ak = *(const bf16x8*)
            &Ks[hh][(i * 16 + l15) * 32 + (quad ^ sw) * 8];
        #pragma unroll
        for (int j = 0; j < 4; ++j)
          s[i][j] = MFMA16(ak, aq[hh][j], s[i][j]);
      }
    __builtin_amdgcn_s_setprio(0);
    __builtin_amdgcn_s_barrier();   // all waves done reading Ks

    const int tn = ((it + 1) & (SEQ / 64 - 1)) << 6;
    #pragma unroll
    for (int hh = 0; hh < 2; ++hh)
      #pragma unroll
      for (int part = 0; part < 2; ++part)
        lds16(kbase + (size_t)(tn + part * 32 + srow) * DHEAD + hh * 32 + gc * 8,
              &Ks[hh][part * 1024 + tid * 8]);
    #pragma unroll
    for (int part = 0; part < 4; ++part)
      lds16(vbase + (size_t)(part * 16 + vd) * SEQ + tn + vc * 8,
            &Vt[cur ^ 1][part * 1024 + tid * 8]);

    // P^T = exp2(S^T), packed straight into PV B-fragments (register-only)
    bf16x8 bp[2][4];
    #pragma unroll
    for (int j = 0; j < 4; ++j) {
      float p[4][4];
      #pragma unroll
      for (int i = 0; i < 4; ++i)
        #pragma unroll
        for (int r = 0; r < 4; ++r)
          p[i][r] = EXP2F(s[i][j][r]);
      u32x4 t0, t1;
      t0.x = cvtpk(p[0][0], p[1][0]); t0.y = cvtpk(p[2][0], p[3][0]);
      t0.z = cvtpk(p[0][1], p[1][1]); t0.w = cvtpk(p[2][1], p[3][1]);
      t1.x = cvtpk(p[0][2], p[1][2]); t1.y = cvtpk(p[2][2], p[3][2]);
      t1.z = cvtpk(p[0][3], p[1][3]); t1.w = cvtpk(p[2][3], p[3][3]);
      bp[0][j] = __builtin_bit_cast(bf16x8, t0);
      bp[1][j] = __builtin_bit_cast(bf16x8, t1);
      lacc[j] = MFMA16(ones8, bp[0][j], lacc[j]);
      lacc[j] = MFMA16(ones8, bp[1][j], lacc[j]);
    }

    asm volatile("s_waitcnt vmcnt(8)" ::: "memory");
    __builtin_amdgcn_s_barrier();

    // O^T += V^T P^T  (32 MFMA, 8 Vt b128 reads, bp from registers)
    __builtin_amdgcn_s_setprio(1);
    #pragma unroll
    for (int hh = 0; hh < 2; ++hh)
      #pragma unroll
      for (int m = 0; m < 4; ++m) {
        const int d = m * 16 + l15;
        const bf16x8 av = *(const bf16x8*)
            &Vt[cur][d * 64 + (((quad * 2 + hh) ^ (d & 7)) << 3)];
        #pragma unroll
        for (int j = 0; j < 4; ++j)
          o[m][j] = MFMA16(av, bp[hh][j], o[m][j]);
      }
    __builtin_amdgcn_s_setprio(0);
    cur ^= 1;
  }
  asm volatile("s_waitcnt vmcnt(0)" ::: "memory");

  float inv[4];
  #pragma unroll
  for (int j = 0; j < 4; ++j)
    inv[j] = 1.f / lacc[j][0];

  #pragma unroll
  for (int m = 0; m < 4; ++m)
    #pragma unroll
    for (int j = 0; j < 4; ++j) {
      u32x2 pk;
      pk.x = cvtpk(o[m][j][0] * inv[j], o[m][j][1] * inv[j]);
      pk.y = cvtpk(o[m][j][2] * inv[j], o[m][j][3] * inv[j]);
      *(u32x2*)&Hidden[(size_t)(b * SEQ + q0 + w * 64 + j * 16 + l15) * HID
                       + h * DHEAD + m * 16 + quad * 4] = pk;
    }
}

extern "C" void kernel_launch(void* const* d_in, const int* in_sizes, int n_in,
                              void* d_out, int out_size, void* d_ws, size_t ws_size,
                              hipStream_t stream) {
  const float* q  = (const float*)d_in[0];
  const float* k  = (const float*)d_in[1];
  const float* v  = (const float*)d_in[2];
  const int* mask = (const int*)d_in[3];
  const float* wq = (const float*)d_in[4];
  const float* bq = (const float*)d_in[5];
  const float* wk = (const float*)d_in[6];
  const float* bk = (const float*)d_in[7];
  const float* wv = (const float*)d_in[8];
  const float* bv = (const float*)d_in[9];
  const float* wo = (const float*)d_in[10];
  const float* bo = (const float*)d_in[11];

  const size_t SEG = (size_t)MROWS * HID;   // 8388608
  const size_t WSEG = (size_t)HID * HID;    // 1048576 = 1<<20
  const dim3 gq(MROWS / 128, HID / 128, 3); // fallback fused QKV
  const dim3 go(MROWS / 128, HID / 128);
  const dim3 ga(SEQ / 128, BATCH * HEADS);  // 16 x 64

  const size_t planFULL = (6 * SEG + 4 * WSEG) * sizeof(u16);  // ~104 MB
  const size_t planMID  = (4 * SEG + 4 * WSEG) * sizeof(u16);  // ~75.5 MB

  if (ws_size >= planFULL) {
    // FULL: everything bf16; pipelined 256x128 GEMMs.
    u16* qb  = (u16*)d_ws;
    u16* kb  = qb + SEG;
    u16* vb  = kb + SEG;
    u16* qh  = vb + SEG;
    u16* kh  = qh + SEG;
    u16* vt  = kh + SEG;
    u16* wqb = vt + SEG;
    u16* wkb = wqb + WSEG;
    u16* wvb = wkb + WSEG;
    u16* wob = wvb + WSEG;
    u16* hidden = qb;  // alias (qb dead after gemm_qkv2)

    CvtArgs ca;
    ca.src[0] = q;  ca.dst[0] = qb;
    ca.src[1] = k;  ca.dst[1] = kb;
    ca.src[2] = v;  ca.dst[2] = vb;
    ca.src[3] = wq; ca.dst[3] = wqb;
    ca.src[4] = wk; ca.dst[4] = wkb;
    ca.src[5] = wv; ca.dst[5] = wvb;
    ca.src[6] = wo; ca.dst[6] = wob;
    cvt7<<<dim3(SEG / 2048, 4), 256, 0, stream>>>(ca, 0, (int)SEG);

    gemm_qkv2<<<dim3(768), 512, 0, stream>>>(qb, kb, vb, wqb, wkb, wvb,
                                             bq, bk, bv, mask, qh, kh, vt);
    attn_mfma<<<ga, 128, 0, stream>>>(qh, kh, vt, hidden);
    gemm_out2<<<dim3(256), 512, 0, stream>>>(hidden, wob, bo, (float*)d_out);
  } else if (ws_size >= planMID) {
    // MID: weights bf16-DMA, fp32 activations VALU-staged (fallback kernels)
    u16* wqb = (u16*)d_ws;
    u16* wkb = wqb + WSEG;
    u16* wvb = wkb + WSEG;
    u16* wob = wvb + WSEG;
    u16* qh = wob + WSEG;
    u16* kh = qh + SEG;
    u16* vt = kh + SEG;
    u16* hidden = vt + SEG;

    CvtArgs ca;
    ca.src[0] = ca.src[1] = ca.src[2] = q;  // unused slots
    ca.dst[0] = ca.dst[1] = ca.dst[2] = wqb;
    ca.src[3] = wq; ca.dst[3] = wqb;
    ca.src[4] = wk; ca.dst[4] = wkb;
    ca.src[5] = wv; ca.dst[5] = wvb;
    ca.src[6] = wo; ca.dst[6] = wob;
    cvt7<<<dim3(4 * WSEG / 2048, 1), 256, 0, stream>>>(ca, 3, 0);

    gemm_qkv<false, true><<<gq, 256, 0, stream>>>(q, k, v, wqb, wkb, wvb,
                                                  bq, bk, bv, mask, qh, kh, vt);
    attn_mfma<<<ga, 128, 0, stream>>>(qh, kh, vt, hidden);
    gemm_out<true><<<go, 256, 0, stream>>>(hidden, wob, bo, (float*)d_out);
  } else {
    // LOW: 64 MiB ws, all fp32 operands VALU-staged
    u16* qh = (u16*)d_ws;
    u16* kh = qh + SEG;
    u16* vt = kh + SEG;
    u16* hidden = vt + SEG;

    gemm_qkv<false, false><<<gq, 256, 0, stream>>>(q, k, v, wq, wk, wv,
                                                   bq, bk, bv, mask, qh, kh, vt);
    attn_mfma<<<ga, 128, 0, stream>>>(qh, kh, vt, hidden);
    gemm_out<false><<<go, 256, 0, stream>>>(hidden, wo, bo, (float*)d_out);
  }
}

// Round 5
// 322.319 us; speedup vs baseline: 1.1108x; 1.0001x over previous
//
#include <hip/hip_runtime.h>

#define BATCH 4
#define SEQ 2048
#define HEADS 16
#define DHEAD 64
#define HID 1024
#define MROWS (BATCH * SEQ)   // 8192
#define QSCALE 0.1803368801111092f   // 0.125 * log2(e): exp2 domain

typedef unsigned short u16;
typedef unsigned int u32;
typedef __attribute__((ext_vector_type(4))) float f32x4;
typedef __attribute__((ext_vector_type(8))) short bf16x8;
typedef __attribute__((ext_vector_type(2))) unsigned int u32x2;
typedef __attribute__((ext_vector_type(4))) unsigned int u32x4;

#define MFMA16(a, b, c) __builtin_amdgcn_mfma_f32_16x16x32_bf16((a), (b), (c), 0, 0, 0)
#define EXP2F(x) __builtin_amdgcn_exp2f(x)

// f32 -> bf16 round-to-nearest-even (finite inputs)
__device__ __forceinline__ u16 f2bf(float f) {
  union { float f; u32 i; } x; x.f = f;
  u32 r = x.i + 0x7fffu + ((x.i >> 16) & 1u);
  return (u16)(r >> 16);
}

// packed f32 pair -> bf16 pair (RNE), one VALU op (T12 primitive).
__device__ __forceinline__ u32 cvtpk(float a, float b) {
  u32 d;
  asm("v_cvt_pk_bf16_f32 %0, %1, %2" : "=v"(d) : "v"(a), "v"(b));
  return d;
}

// async global->LDS, 16 B/lane.  LDS dest must be wave-uniform base + lane*16.
__device__ __forceinline__ void lds16(const u16* g, u16* s) {
  __builtin_amdgcn_global_load_lds(
      (const __attribute__((address_space(1))) void*)g,
      (__attribute__((address_space(3))) void*)s, 16, 0, 0);
}

// VALU staging: 8 fp32 -> 8 bf16 (fallback paths + cvt kernel)
__device__ __forceinline__ void stage8f(const float* __restrict__ g, u16* s) {
  const float4 a = *(const float4*)g;
  const float4 b = *(const float4*)(g + 4);
  ushort4 lo, hi;
  lo.x = f2bf(a.x); lo.y = f2bf(a.y); lo.z = f2bf(a.z); lo.w = f2bf(a.w);
  hi.x = f2bf(b.x); hi.y = f2bf(b.y); hi.z = f2bf(b.z); hi.w = f2bf(b.w);
  *(ushort4*)s = lo;
  *(ushort4*)(s + 4) = hi;
}

// fp32 -> bf16 for up to 7 tensors in one launch.
struct CvtArgs {
  const float* src[7];
  u16* dst[7];
};
__global__ __launch_bounds__(256) void cvt7(CvtArgs args, int yoff, int nact) {
  const int y = blockIdx.y + yoff;
  const int i = (blockIdx.x * 256 + threadIdx.x) * 8;
  if (y < 3) {
    if (i < nact) stage8f(args.src[y] + i, args.dst[y] + i);
  } else {
    if (i < 4 * (1 << 20)) {
      const int j = i >> 20, off = i & ((1 << 20) - 1);
      stage8f(args.src[3 + j] + off, args.dst[3 + j] + off);
    }
  }
}

// ---------------------------------------------------------------------------
// OLD 128x128x(BK=32) core -- kept for the MID/LOW fallback paths only.
// ---------------------------------------------------------------------------
template<bool ADMA, bool BDMA>
__device__ __forceinline__ void gemm_core(
    const void* __restrict__ Av, const void* __restrict__ Wv,
    int tid, int m0, int n0, u16* As, u16* Bs, f32x4 (&acc)[4][4])
{
  const int srow = tid >> 2, cslot = tid & 3;
  const int gc = cslot ^ ((srow >> 1) & 3);   // swizzled global chunk
  const int w = tid >> 6, l = tid & 63;
  const int quad = l >> 4, l15 = l & 15;
  const int sw = (l15 >> 1) & 3;
  const int wm = (w & 1) << 6, wn = (w >> 1) << 6;

  for (int k0 = 0; k0 < HID; k0 += 32) {
    if (ADMA) {
      const u16* ag = (const u16*)Av + (size_t)(m0 + srow) * HID + k0 + gc * 8;
      lds16(ag, &As[tid * 8]);
      lds16(ag + (size_t)64 * HID, &As[2048 + tid * 8]);
    } else {
      const float* ag = (const float*)Av + (size_t)(m0 + srow) * HID + k0 + gc * 8;
      stage8f(ag, &As[srow * 32 + cslot * 8]);
      stage8f(ag + (size_t)64 * HID, &As[(64 + srow) * 32 + cslot * 8]);
    }
    if (BDMA) {
      const u16* bg = (const u16*)Wv + (size_t)(n0 + srow) * HID + k0 + gc * 8;
      lds16(bg, &Bs[tid * 8]);
      lds16(bg + (size_t)64 * HID, &Bs[2048 + tid * 8]);
    } else {
      const float* bg = (const float*)Wv + (size_t)(n0 + srow) * HID + k0 + gc * 8;
      stage8f(bg, &Bs[srow * 32 + cslot * 8]);
      stage8f(bg + (size_t)64 * HID, &Bs[(64 + srow) * 32 + cslot * 8]);
    }
    __syncthreads();

    bf16x8 a[4], b[4];
    #pragma unroll
    for (int i = 0; i < 4; ++i)
      a[i] = *(const bf16x8*)&As[(wm + i * 16 + l15) * 32 + (quad ^ sw) * 8];
    #pragma unroll
    for (int j = 0; j < 4; ++j)
      b[j] = *(const bf16x8*)&Bs[(wn + j * 16 + l15) * 32 + (quad ^ sw) * 8];
    #pragma unroll
    for (int i = 0; i < 4; ++i)
      #pragma unroll
      for (int j = 0; j < 4; ++j)
        acc[i][j] = MFMA16(a[i], b[j], acc[i][j]);
    __syncthreads();
  }
}

// Fallback fused QKV (MID/LOW).  Epilogue semantics documented at gemm_qkv2.
template<bool ADMA, bool BDMA>
__global__ __launch_bounds__(256) void gemm_qkv(
    const void* __restrict__ xq, const void* __restrict__ xk,
    const void* __restrict__ xv,
    const void* __restrict__ wqv, const void* __restrict__ wkv,
    const void* __restrict__ wvv,
    const float* __restrict__ bq, const float* __restrict__ bk,
    const float* __restrict__ bv, const int* __restrict__ Mask,
    u16* __restrict__ qh, u16* __restrict__ kh, u16* __restrict__ vt)
{
  __shared__ u16 As[128 * 32];
  __shared__ u16 Bs[128 * 32];
  const int z = blockIdx.z;
  const void* A = (z == 0) ? xq : (z == 1) ? xk : xv;
  const void* W = (z == 0) ? wqv : (z == 1) ? wkv : wvv;
  const float* Bias = (z == 0) ? bq : (z == 1) ? bk : bv;

  const int tid = threadIdx.x;
  const int m0 = blockIdx.x << 7, n0 = blockIdx.y << 7;
  f32x4 acc[4][4] = {};
  gemm_core<ADMA, BDMA>(A, W, tid, m0, n0, As, Bs, acc);

  const int w = tid >> 6, l = tid & 63;
  const int quad = l >> 4, l15 = l & 15;
  const int wm = (w & 1) << 6, wn = (w >> 1) << 6;

  if (z <= 1) {
    u16* Out = (z == 0) ? qh : kh;
    #pragma unroll
    for (int i = 0; i < 4; ++i) {
      float fl[4];
      #pragma unroll
      for (int r = 0; r < 4; ++r) {
        const int m = m0 + wm + i * 16 + (quad << 2) + r;
        fl[r] = (z == 0) ? (Mask[m] ? QSCALE : 0.f) : 1.f;
      }
      #pragma unroll
      for (int j = 0; j < 4; ++j) {
        const int n = n0 + wn + j * 16 + l15;
        const float bias = Bias[n];
        const int h = n >> 6, d = n & 63;
        #pragma unroll
        for (int r = 0; r < 4; ++r) {
          const int m = m0 + wm + i * 16 + (quad << 2) + r;
          const int bb = m >> 11, s = m & (SEQ - 1);
          Out[((size_t)(bb * HEADS + h) * SEQ + s) * DHEAD + d] =
              f2bf((acc[i][j][r] + bias) * fl[r]);
        }
      }
    }
  } else {
    const int sblk = (m0 + wm) & (SEQ - 1);
    const int bb = (m0 + wm) >> 11;
    #pragma unroll
    for (int j = 0; j < 4; ++j) {
      const int n = n0 + wn + j * 16 + l15;
      const float bias = Bias[n];
      const int h = n >> 6, d = n & 63;
      u16* base = vt + ((size_t)(bb * HEADS + h) * DHEAD + d) * SEQ + sblk;
      #pragma unroll
      for (int r = 0; r < 4; ++r) {
        u32x2 pk;
        pk.x = cvtpk(acc[0][j][r] + bias, acc[1][j][r] + bias);
        pk.y = cvtpk(acc[2][j][r] + bias, acc[3][j][r] + bias);
        *(u32x2*)(base + ((quad << 2) + r) * 4) = pk;
      }
    }
  }
}

// Fallback output projection (MID/LOW)
template<bool BDMA>
__global__ __launch_bounds__(256) void gemm_out(
    const u16* __restrict__ hidden, const void* __restrict__ wov,
    const float* __restrict__ bo, float* __restrict__ Out)
{
  __shared__ u16 As[128 * 32];
  __shared__ u16 Bs[128 * 32];
  const int tid = threadIdx.x;
  const int m0 = blockIdx.x << 7, n0 = blockIdx.y << 7;
  f32x4 acc[4][4] = {};
  gemm_core<true, BDMA>(hidden, wov, tid, m0, n0, As, Bs, acc);

  const int w = tid >> 6, l = tid & 63;
  const int quad = l >> 4, l15 = l & 15;
  const int wm = (w & 1) << 6, wn = (w >> 1) << 6;
  #pragma unroll
  for (int j = 0; j < 4; ++j) {
    const int n = n0 + wn + j * 16 + l15;
    const float bias = bo[n];
    #pragma unroll
    for (int i = 0; i < 4; ++i) {
      const int mb = m0 + wm + i * 16 + (quad << 2);
      #pragma unroll
      for (int r = 0; r < 4; ++r)
        Out[(size_t)(mb + r) * HID + n] = acc[i][j][r] + bias;
    }
  }
}

// ---------------------------------------------------------------------------
// Pipelined 256x128x(BK=64) core (FULL path).  512 thr = 8 waves (4M x 2N),
// wave tile 64x64 (acc 4x4 f32x4).  TRIPLE-buffered LDS (144 KB), 2-deep
// counted-vmcnt prefetch (T3/T4: never drain to 0 in the loop):
//   prologue: stage tile0->buf0, tile1->buf1          (12 loads in flight)
//   iter t:   s_waitcnt vmcnt(6)  -- oldest 6 = tile t landed; tile t+1
//             barrier                stays in flight across the barrier
//             issue stage(t+2 -> buf[(t+2)%3])        (6 global_load_lds)
//             ks=0,1: 12 ds_read_b128 + 32 MFMA (setprio-wrapped)
// Each staged tile gets TWO compute phases (~2400 cyc) to cover L2/HBM
// latency, vs one in the R4 depth-1 version (which left MfmaUtil at 27%).
// WAR on buf[(t+2)%3] is safe: it was read at iter t-1; those ds_reads
// retired (lgkmcnt) before iter t-1's MFMAs, hence before the iter-t
// barrier that precedes this stage.  Full unroll -> all vmcnt immediates
// and buffer offsets are compile-time.  LDS rows are 128 B -> 8-slot XOR
// swizzle slot = chunk ^ (row&7), applied on BOTH sides: pre-swizzled
// global source (linear DMA dest) + swizzled ds_read address.
// ---------------------------------------------------------------------------
__device__ __forceinline__ void core256(
    const u16* __restrict__ A, const u16* __restrict__ W,
    int tid, int m0, int n0, u16* As2, u16* Bs2, f32x4 (&acc)[4][4])
{
  const int l = tid & 63;
  const int quad = l >> 4, l15 = l & 15;
  const int sw7 = l15 & 7;
  const int w = tid >> 6;
  const int wm = (w & 3) << 6, wn = (w >> 2) << 6;
  const int srow = tid >> 3, sslot = tid & 7;   // staging: row-in-part, slot
  const int sgc = sslot ^ (srow & 7);           // content chunk (global side)

  const u16* aB = A + (size_t)(m0 + srow) * HID + sgc * 8;
  const u16* bB = W + (size_t)(n0 + srow) * HID + sgc * 8;

  // prologue: tiles 0,1 -> buffers 0,1 (order: per-tile A then B, 6 loads/tile)
  #pragma unroll
  for (int tt = 0; tt < 2; ++tt) {
    #pragma unroll
    for (int p = 0; p < 4; ++p)
      lds16(aB + (size_t)p * 64 * HID + tt * 64,
            As2 + tt * 16384 + p * 4096 + tid * 8);
    #pragma unroll
    for (int p = 0; p < 2; ++p)
      lds16(bB + (size_t)p * 64 * HID + tt * 64,
            Bs2 + tt * 8192 + p * 4096 + tid * 8);
  }

  #pragma unroll
  for (int t = 0; t < HID / 64; ++t) {
    if (t < HID / 64 - 1)
      asm volatile("s_waitcnt vmcnt(6)" ::: "memory");  // tile t landed
    else
      asm volatile("s_waitcnt vmcnt(0)" ::: "memory");  // last tile
    __builtin_amdgcn_s_barrier();                       // publish tile t
    __builtin_amdgcn_sched_barrier(0);

    if (t < HID / 64 - 2) {   // stage tile t+2 into the 3rd buffer
      const int kk = (t + 2) << 6;
      u16* ad = As2 + ((t + 2) % 3) * 16384;
      u16* bd = Bs2 + ((t + 2) % 3) * 8192;
      #pragma unroll
      for (int p = 0; p < 4; ++p)
        lds16(aB + (size_t)p * 64 * HID + kk, ad + p * 4096 + tid * 8);
      #pragma unroll
      for (int p = 0; p < 2; ++p)
        lds16(bB + (size_t)p * 64 * HID + kk, bd + p * 4096 + tid * 8);
    }

    const u16* Ab = As2 + (t % 3) * 16384;
    const u16* Bb = Bs2 + (t % 3) * 8192;
    #pragma unroll
    for (int ks = 0; ks < 2; ++ks) {
      const int cc = ((ks << 2) | quad) ^ sw7;
      bf16x8 a[4], b[4];
      #pragma unroll
      for (int i = 0; i < 4; ++i)
        a[i] = *(const bf16x8*)&Ab[(wm + i * 16 + l15) * 64 + cc * 8];
      #pragma unroll
      for (int j = 0; j < 4; ++j)
        b[j] = *(const bf16x8*)&Bb[(wn + j * 16 + l15) * 64 + cc * 8];
      __builtin_amdgcn_s_setprio(1);
      #pragma unroll
      for (int i = 0; i < 4; ++i)
        #pragma unroll
        for (int j = 0; j < 4; ++j)
          acc[i][j] = MFMA16(a[i], b[j], acc[i][j]);
      __builtin_amdgcn_s_setprio(0);
    }
  }
  asm volatile("s_waitcnt vmcnt(0)" ::: "memory");  // drain before LDS death
}

// Fused QKV projection, pipelined core.  768 blocks = 3 exact rounds at
// 1 block/CU.  XCD-chunked bijective remap: nid = (lin&7)*96 + lin>>3, so
// each XCD's L2 sees consecutive n-tiles of the same 512 KB A-panel.
// Epilogues: z=0 mask*QSCALE; z=2 V^T key-perm (see attn_mfma notes).
__global__ __launch_bounds__(512, 1) void gemm_qkv2(
    const u16* __restrict__ xq, const u16* __restrict__ xk,
    const u16* __restrict__ xv,
    const u16* __restrict__ wqv, const u16* __restrict__ wkv,
    const u16* __restrict__ wvv,
    const float* __restrict__ bq, const float* __restrict__ bk,
    const float* __restrict__ bv, const int* __restrict__ Mask,
    u16* __restrict__ qh, u16* __restrict__ kh, u16* __restrict__ vt)
{
  __shared__ u16 As2[3 * 16384];  // 96 KB
  __shared__ u16 Bs2[3 * 8192];   // 48 KB
  const int tid = threadIdx.x;

  const int lin = blockIdx.x;
  const int nid = (lin & 7) * 96 + (lin >> 3);
  const int z = nid >> 8;
  const int rem = nid & 255;
  const int m0 = (rem >> 3) << 8, n0 = (rem & 7) << 7;

  const u16* A = (z == 0) ? xq : (z == 1) ? xk : xv;
  const u16* W = (z == 0) ? wqv : (z == 1) ? wkv : wvv;
  const float* Bias = (z == 0) ? bq : (z == 1) ? bk : bv;

  f32x4 acc[4][4] = {};
  core256(A, W, tid, m0, n0, As2, Bs2, acc);

  const int w = tid >> 6, l = tid & 63;
  const int quad = l >> 4, l15 = l & 15;
  const int wm = (w & 3) << 6, wn = (w >> 2) << 6;

  if (z <= 1) {
    u16* Out = (z == 0) ? qh : kh;
    #pragma unroll
    for (int i = 0; i < 4; ++i) {
      float fl[4];
      #pragma unroll
      for (int r = 0; r < 4; ++r) {
        const int m = m0 + wm + i * 16 + (quad << 2) + r;
        fl[r] = (z == 0) ? (Mask[m] ? QSCALE : 0.f) : 1.f;
      }
      #pragma unroll
      for (int j = 0; j < 4; ++j) {
        const int n = n0 + wn + j * 16 + l15;
        const float bias = Bias[n];
        const int h = n >> 6, d = n & 63;
        #pragma unroll
        for (int r = 0; r < 4; ++r) {
          const int m = m0 + wm + i * 16 + (quad << 2) + r;
          const int bb = m >> 11, s = m & (SEQ - 1);
          Out[((size_t)(bb * HEADS + h) * SEQ + s) * DHEAD + d] =
              f2bf((acc[i][j][r] + bias) * fl[r]);
        }
      }
    }
  } else {
    const int sblk = (m0 + wm) & (SEQ - 1);
    const int bb = (m0 + wm) >> 11;
    #pragma unroll
    for (int j = 0; j < 4; ++j) {
      const int n = n0 + wn + j * 16 + l15;
      const float bias = Bias[n];
      const int h = n >> 6, d = n & 63;
      u16* base = vt + ((size_t)(bb * HEADS + h) * DHEAD + d) * SEQ + sblk;
      #pragma unroll
      for (int r = 0; r < 4; ++r) {
        u32x2 pk;
        pk.x = cvtpk(acc[0][j][r] + bias, acc[1][j][r] + bias);
        pk.y = cvtpk(acc[2][j][r] + bias, acc[3][j][r] + bias);
        *(u32x2*)(base + ((quad << 2) + r) * 4) = pk;
      }
    }
  }
}

// Output projection, pipelined core.  256 blocks = 1 exact round.
__global__ __launch_bounds__(512, 1) void gemm_out2(
    const u16* __restrict__ hidden, const u16* __restrict__ wov,
    const float* __restrict__ bo, float* __restrict__ Out)
{
  __shared__ u16 As2[3 * 16384];
  __shared__ u16 Bs2[3 * 8192];
  const int tid = threadIdx.x;

  const int lin = blockIdx.x;
  const int nid = (lin & 7) * 32 + (lin >> 3);
  const int m0 = (nid >> 3) << 8, n0 = (nid & 7) << 7;

  f32x4 acc[4][4] = {};
  core256(hidden, wov, tid, m0, n0, As2, Bs2, acc);

  const int w = tid >> 6, l = tid & 63;
  const int quad = l >> 4, l15 = l & 15;
  const int wm = (w & 3) << 6, wn = (w >> 2) << 6;
  #pragma unroll
  for (int j = 0; j < 4; ++j) {
    const int n = n0 + wn + j * 16 + l15;
    const float bias = bo[n];
    #pragma unroll
    for (int i = 0; i < 4; ++i) {
      const int mb = m0 + wm + i * 16 + (quad << 2);
      #pragma unroll
      for (int r = 0; r < 4; ++r)
        Out[(size_t)(mb + r) * HID + n] = acc[i][j][r] + bias;
    }
  }
}

// Flash attention, no-max softmax, SWAPPED-OPERAND form (zero P LDS traffic).
// S^T = mfma(K,Q); P^T packed in-register feeds O^T = mfma(V^T, P^T);
// denominator via mfma(ones, P^T).  Counted-vmcnt pipeline, raw barriers.
__global__ __launch_bounds__(128, 2) void attn_mfma(
    const u16* __restrict__ QH, const u16* __restrict__ KH,
    const u16* __restrict__ VT, u16* __restrict__ Hidden)
{
  __shared__ u16 Qs[2][128 * 32];  // 16 KB (dead after prologue)
  __shared__ u16 Ks[2][2048];      // 8 KB, single-buffered (restage post-QK)
  __shared__ u16 Vt[2][4096];      // 16 KB: [buf][64 d][64 key-slots], swizzled

  const int tid = threadIdx.x;     // 0..127
  const int w = tid >> 6, l = tid & 63;
  const int quad = l >> 4, l15 = l & 15;
  const int sw = (l15 >> 1) & 3;
  const int srow = tid >> 2, cslot = tid & 3;
  const int gc = cslot ^ ((srow >> 1) & 3);   // K/Q staging swizzle
  const int vd = tid >> 3;                    // V staging: row within part
  const int vc = (tid & 7) ^ (vd & 7);        // V staging: content chunk

  const int lin = blockIdx.y * 16 + blockIdx.x;
  const int bh = lin & 63, b = bh >> 4, h = bh & 15;
  const int q0 = (lin >> 6) << 7;

  const u16* qbase = QH + (size_t)bh * SEQ * DHEAD;
  const u16* kbase = KH + (size_t)bh * SEQ * DHEAD;
  const u16* vbase = VT + (size_t)bh * DHEAD * SEQ;

  #pragma unroll
  for (int hh = 0; hh < 2; ++hh)
    #pragma unroll
    for (int part = 0; part < 4; ++part)
      lds16(qbase + (size_t)(q0 + part * 32 + srow) * DHEAD + hh * 32 + gc * 8,
            &Qs[hh][part * 1024 + tid * 8]);
  #pragma unroll
  for (int hh = 0; hh < 2; ++hh)
    #pragma unroll
    for (int part = 0; part < 2; ++part)
      lds16(kbase + (size_t)(part * 32 + srow) * DHEAD + hh * 32 + gc * 8,
            &Ks[hh][part * 1024 + tid * 8]);
  #pragma unroll
  for (int part = 0; part < 4; ++part)
    lds16(vbase + (size_t)(part * 16 + vd) * SEQ + vc * 8,
          &Vt[0][part * 1024 + tid * 8]);
  asm volatile("s_waitcnt vmcnt(8)" ::: "memory");  // Q landed; K0/V0 in flight
  __builtin_amdgcn_s_barrier();

  bf16x8 aq[2][4];
  #pragma unroll
  for (int hh = 0; hh < 2; ++hh)
    #pragma unroll
    for (int j = 0; j < 4; ++j)
      aq[hh][j] = *(const bf16x8*)
          &Qs[hh][(w * 64 + j * 16 + l15) * 32 + (quad ^ sw) * 8];

  const bf16x8 ones8 = {0x3F80, 0x3F80, 0x3F80, 0x3F80,
                        0x3F80, 0x3F80, 0x3F80, 0x3F80};  // bf16 1.0 x8
  f32x4 o[4][4] = {};      // O^T accum: [d-tile][q-tile]
  f32x4 lacc[4] = {};      // denominator accum per q-tile
  int cur = 0;

  for (int it = 0; it < SEQ / 64; ++it) {
    asm volatile("s_waitcnt vmcnt(4)" ::: "memory");
    __builtin_amdgcn_s_barrier();

    // S^T = K Q^T (log2-domain): 32 MFMA, 8 Ks reads
    f32x4 s[4][4] = {};
    __builtin_amdgcn_s_setprio(1);
    #pragma unroll
    for (int i = 0; i < 4; ++i)
      #pragma unroll
      for (int hh = 0; hh < 2; ++hh) {
        const bf16x8 ak = *(const bf16x8*)
            &Ks[hh][(i * 16 + l15) * 32 + (quad ^ sw) * 8];
        #pragma unroll
        for (int j = 0; j < 4; ++j)
          s[i][j] = MFMA16(ak, aq[hh][j], s[i][j]);
      }
    __builtin_amdgcn_s_setprio(0);
    __builtin_amdgcn_s_barrier();   // all waves done reading Ks

    const int tn = ((it + 1) & (SEQ / 64 - 1)) << 6;
    #pragma unroll
    for (int hh = 0; hh < 2; ++hh)
      #pragma unroll
      for (int part = 0; part < 2; ++part)
        lds16(kbase + (size_t)(tn + part * 32 + srow) * DHEAD + hh * 32 + gc * 8,
              &Ks[hh][part * 1024 + tid * 8]);
    #pragma unroll
    for (int part = 0; part < 4; ++part)
      lds16(vbase + (size_t)(part * 16 + vd) * SEQ + tn + vc * 8,
            &Vt[cur ^ 1][part * 1024 + tid * 8]);

    // P^T = exp2(S^T), packed straight into PV B-fragments (register-only)
    bf16x8 bp[2][4];
    #pragma unroll
    for (int j = 0; j < 4; ++j) {
      float p[4][4];
      #pragma unroll
      for (int i = 0; i < 4; ++i)
        #pragma unroll
        for (int r = 0; r < 4; ++r)
          p[i][r] = EXP2F(s[i][j][r]);
      u32x4 t0, t1;
      t0.x = cvtpk(p[0][0], p[1][0]); t0.y = cvtpk(p[2][0], p[3][0]);
      t0.z = cvtpk(p[0][1], p[1][1]); t0.w = cvtpk(p[2][1], p[3][1]);
      t1.x = cvtpk(p[0][2], p[1][2]); t1.y = cvtpk(p[2][2], p[3][2]);
      t1.z = cvtpk(p[0][3], p[1][3]); t1.w = cvtpk(p[2][3], p[3][3]);
      bp[0][j] = __builtin_bit_cast(bf16x8, t0);
      bp[1][j] = __builtin_bit_cast(bf16x8, t1);
      lacc[j] = MFMA16(ones8, bp[0][j], lacc[j]);
      lacc[j] = MFMA16(ones8, bp[1][j], lacc[j]);
    }

    asm volatile("s_waitcnt vmcnt(8)" ::: "memory");
    __builtin_amdgcn_s_barrier();

    // O^T += V^T P^T  (32 MFMA, 8 Vt b128 reads, bp from registers)
    __builtin_amdgcn_s_setprio(1);
    #pragma unroll
    for (int hh = 0; hh < 2; ++hh)
      #pragma unroll
      for (int m = 0; m < 4; ++m) {
        const int d = m * 16 + l15;
        const bf16x8 av = *(const bf16x8*)
            &Vt[cur][d * 64 + (((quad * 2 + hh) ^ (d & 7)) << 3)];
        #pragma unroll
        for (int j = 0; j < 4; ++j)
          o[m][j] = MFMA16(av, bp[hh][j], o[m][j]);
      }
    __builtin_amdgcn_s_setprio(0);
    cur ^= 1;
  }
  asm volatile("s_waitcnt vmcnt(0)" ::: "memory");

  float inv[4];
  #pragma unroll
  for (int j = 0; j < 4; ++j)
    inv[j] = 1.f / lacc[j][0];

  #pragma unroll
  for (int m = 0; m < 4; ++m)
    #pragma unroll
    for (int j = 0; j < 4; ++j) {
      u32x2 pk;
      pk.x = cvtpk(o[m][j][0] * inv[j], o[m][j][1] * inv[j]);
      pk.y = cvtpk(o[m][j][2] * inv[j], o[m][j][3] * inv[j]);
      *(u32x2*)&Hidden[(size_t)(b * SEQ + q0 + w * 64 + j * 16 + l15) * HID
                       + h * DHEAD + m * 16 + quad * 4] = pk;
    }
}

extern "C" void kernel_launch(void* const* d_in, const int* in_sizes, int n_in,
                              void* d_out, int out_size, void* d_ws, size_t ws_size,
                              hipStream_t stream) {
  const float* q  = (const float*)d_in[0];
  const float* k  = (const float*)d_in[1];
  const float* v  = (const float*)d_in[2];
  const int* mask = (const int*)d_in[3];
  const float* wq = (const float*)d_in[4];
  const float* bq = (const float*)d_in[5];
  const float* wk = (const float*)d_in[6];
  const float* bk = (const float*)d_in[7];
  const float* wv = (const float*)d_in[8];
  const float* bv = (const float*)d_in[9];
  const float* wo = (const float*)d_in[10];
  const float* bo = (const float*)d_in[11];

  const size_t SEG = (size_t)MROWS * HID;   // 8388608
  const size_t WSEG = (size_t)HID * HID;    // 1048576 = 1<<20
  const dim3 gq(MROWS / 128, HID / 128, 3); // fallback fused QKV
  const dim3 go(MROWS / 128, HID / 128);
  const dim3 ga(SEQ / 128, BATCH * HEADS);  // 16 x 64

  const size_t planFULL = (6 * SEG + 4 * WSEG) * sizeof(u16);  // ~104 MB
  const size_t planMID  = (4 * SEG + 4 * WSEG) * sizeof(u16);  // ~75.5 MB

  if (ws_size >= planFULL) {
    // FULL: everything bf16; pipelined 256x128 GEMMs (triple-buffered).
    u16* qb  = (u16*)d_ws;
    u16* kb  = qb + SEG;
    u16* vb  = kb + SEG;
    u16* qh  = vb + SEG;
    u16* kh  = qh + SEG;
    u16* vt  = kh + SEG;
    u16* wqb = vt + SEG;
    u16* wkb = wqb + WSEG;
    u16* wvb = wkb + WSEG;
    u16* wob = wvb + WSEG;
    u16* hidden = qb;  // alias (qb dead after gemm_qkv2)

    CvtArgs ca;
    ca.src[0] = q;  ca.dst[0] = qb;
    ca.src[1] = k;  ca.dst[1] = kb;
    ca.src[2] = v;  ca.dst[2] = vb;
    ca.src[3] = wq; ca.dst[3] = wqb;
    ca.src[4] = wk; ca.dst[4] = wkb;
    ca.src[5] = wv; ca.dst[5] = wvb;
    ca.src[6] = wo; ca.dst[6] = wob;
    cvt7<<<dim3(SEG / 2048, 4), 256, 0, stream>>>(ca, 0, (int)SEG);

    gemm_qkv2<<<dim3(768), 512, 0, stream>>>(qb, kb, vb, wqb, wkb, wvb,
                                             bq, bk, bv, mask, qh, kh, vt);
    attn_mfma<<<ga, 128, 0, stream>>>(qh, kh, vt, hidden);
    gemm_out2<<<dim3(256), 512, 0, stream>>>(hidden, wob, bo, (float*)d_out);
  } else if (ws_size >= planMID) {
    // MID: weights bf16-DMA, fp32 activations VALU-staged (fallback kernels)
    u16* wqb = (u16*)d_ws;
    u16* wkb = wqb + WSEG;
    u16* wvb = wkb + WSEG;
    u16* wob = wvb + WSEG;
    u16* qh = wob + WSEG;
    u16* kh = qh + SEG;
    u16* vt = kh + SEG;
    u16* hidden = vt + SEG;

    CvtArgs ca;
    ca.src[0] = ca.src[1] = ca.src[2] = q;  // unused slots
    ca.dst[0] = ca.dst[1] = ca.dst[2] = wqb;
    ca.src[3] = wq; ca.dst[3] = wqb;
    ca.src[4] = wk; ca.dst[4] = wkb;
    ca.src[5] = wv; ca.dst[5] = wvb;
    ca.src[6] = wo; ca.dst[6] = wob;
    cvt7<<<dim3(4 * WSEG / 2048, 1), 256, 0, stream>>>(ca, 3, 0);

    gemm_qkv<false, true><<<gq, 256, 0, stream>>>(q, k, v, wqb, wkb, wvb,
                                                  bq, bk, bv, mask, qh, kh, vt);
    attn_mfma<<<ga, 128, 0, stream>>>(qh, kh, vt, hidden);
    gemm_out<true><<<go, 256, 0, stream>>>(hidden, wob, bo, (float*)d_out);
  } else {
    // LOW: 64 MiB ws, all fp32 operands VALU-staged
    u16* qh = (u16*)d_ws;
    u16* kh = qh + SEG;
    u16* vt = kh + SEG;
    u16* hidden = vt + SEG;

    gemm_qkv<false, false><<<gq, 256, 0, stream>>>(q, k, v, wq, wk, wv,
                                                   bq, bk, bv, mask, qh, kh, vt);
    attn_mfma<<<ga, 128, 0, stream>>>(qh, kh, vt, hidden);
    gemm_out<false><<<go, 256, 0, stream>>>(hidden, wo, bo, (float*)d_out);
  }
}